// Round 7
// baseline (1382.473 us; speedup 1.0000x reference)
//
#include <hip/hip_runtime.h>
#include <stdint.h>

typedef uint32_t u32;
typedef uint64_t u64;

#define VN 50000
#define FN 100000
#define K3F 300000
#define EMAX 300000
#define NB1 1172          // ceil(300000/256); NB1*256 = 300032
#define NBS 293           // 293*1024 = 300032
#define NBH 293
#define NBC 98            // ceil(100000/1024)
#define HALF1 150016      // 586*256
#define NBL 586

// ---------------- workspace layout (u32 units) ----------------
#define W_KPA    0u        // 600000 (300000 u64) ping
#define W_KPB    600000u   // 600000 pong
#define W_SEGOFF 1200000u  // 300001
#define W_FEID   1500004u  // 300000
#define W_XE     1800004u  // 900000 f32
#define W_PK     2700004u  // 3072 f32 packed weights
#define W_P      2703076u  // 600000 f32
#define W_Q      3303076u  // 600000 f32
#define W_Y      3903076u  // 300000 f32
#define W_YMAP   4203076u  // 300000
#define W_SEL    4503076u  // 300000
#define W_SELR   4803076u  // 300000
#define W_CAT    5103076u  // 100000
#define W_CATR   5203076u  // 100000
#define W_NFI    5303076u  // 1200000 int
#define W_HIST   6503076u  // 300032
#define W_HIST2  6803108u  // 300032
#define W_SUMS   7103140u  // 4096 (even offset -> u64-reusable)
#define W_CATH   7107236u  // 1024
#define W_TKH    7108260u  // 256
#define W_DONE   7108516u  // 32 (barrier cnt/gen slots)
#define W_SCAL   7108548u  // 64

#define S_E 0
#define S_NUM 1
#define S_PFX 2
#define S_KREM 3
#define S_TU 4
#define S_R 5
#define S_NF 6
#define S_NEN 7
#define S_O1 8
#define S_O2 9
#define S_O3 10
#define S_RS 16
#define S_GS 24
#define S_GP 32

// device-scope atomic helpers (per-XCD L2s are NOT coherent for plain ld/st — G16)
#define ALDR(p)    __hip_atomic_load((p), __ATOMIC_RELAXED, __HIP_MEMORY_SCOPE_AGENT)
#define ASTR(p,v)  __hip_atomic_store((p), (v), __ATOMIC_RELAXED, __HIP_MEMORY_SCOPE_AGENT)

// grid barrier: generation counter; safe because every fused grid is fully co-resident
__device__ __forceinline__ void gridbar(u32* cnt, u32* gen, u32 nb) {
  __syncthreads();
  if (threadIdx.x == 0) {
    u32 g = __hip_atomic_load(gen, __ATOMIC_ACQUIRE, __HIP_MEMORY_SCOPE_AGENT);
    u32 old = __hip_atomic_fetch_add(cnt, 1u, __ATOMIC_ACQ_REL, __HIP_MEMORY_SCOPE_AGENT);
    if (old == nb - 1u) {
      __hip_atomic_store(cnt, 0u, __ATOMIC_RELAXED, __HIP_MEMORY_SCOPE_AGENT);
      __hip_atomic_fetch_add(gen, 1u, __ATOMIC_RELEASE, __HIP_MEMORY_SCOPE_AGENT);
    } else {
      while (__hip_atomic_load(gen, __ATOMIC_ACQUIRE, __HIP_MEMORY_SCOPE_AGENT) == g)
        __builtin_amdgcn_s_sleep(2);
    }
  }
  __syncthreads();
}

// ---------------- threefry2x32, key = (0, 42) ----------------
__device__ __forceinline__ void tf2x32(u32 x0, u32 x1, u32& o0, u32& o1) {
  const u32 ks0 = 0u, ks1 = 42u, ks2 = 0x1BD11BDAu ^ 0u ^ 42u;
  x0 += ks0; x1 += ks1;
#define TFR(r) { x0 += x1; x1 = (x1<<(r))|(x1>>(32-(r))); x1 ^= x0; }
  TFR(13) TFR(15) TFR(26) TFR(6)   x0 += ks1; x1 += ks2 + 1u;
  TFR(17) TFR(29) TFR(16) TFR(24)  x0 += ks2; x1 += ks0 + 2u;
  TFR(13) TFR(15) TFR(26) TFR(6)   x0 += ks0; x1 += ks1 + 3u;
  TFR(17) TFR(29) TFR(16) TFR(24)  x0 += ks1; x1 += ks2 + 4u;
  TFR(13) TFR(15) TFR(26) TFR(6)   x0 += ks2; x1 += ks0 + 5u;
#undef TFR
  o0 = x0; o1 = x1;
}

// ---------------- k_keys: keys + pass-0 hist + weight pack + inits ----------------
__global__ void k_keys(const int* __restrict__ face,
                       const float* __restrict__ W1s, const float* __restrict__ W1n,
                       const float* __restrict__ b1,
                       const float* __restrict__ W2s, const float* __restrict__ W2n,
                       float* __restrict__ pk,
                       u64* __restrict__ kp, u32* __restrict__ hist,
                       u32* __restrict__ tkh, u32* __restrict__ done) {
  __shared__ u32 h[256];
  int t = threadIdx.x;
  h[t] = 0;
  __syncthreads();
  if (blockIdx.x == 0) {
    tkh[t] = 0u;
    if (t < 32) done[t] = 0u;
    float* p = pk + t*12;
    p[0] = W1s[t]; p[1] = W1s[256+t]; p[2] = W1s[512+t];
    p[3] = W1n[t]; p[4] = W1n[256+t]; p[5] = W1n[512+t];
    p[6] = b1[t];
    p[7] = W2s[2*t]; p[8] = W2s[2*t+1];
    p[9] = W2n[2*t]; p[10] = W2n[2*t+1];
    p[11] = 0.0f;
  }
  int i = blockIdx.x*256 + t;
  if (i < K3F) {
    int s = i / FN, f = i - s*FN;
    int v0 = face[f*3 + s];
    int v1 = face[f*3 + (s == 2 ? 0 : s+1)];
    int a = min(v0, v1), b = max(v0, v1);
    u32 key = ((u32)a * (u32)VN + (u32)b) ^ 0x80000000u;  // biased int32-wrap key
    kp[i] = ((u64)key << 32) | (u32)i;                     // payload = orig index
    atomicAdd(&h[key & 255u], 1u);
  }
  __syncthreads();
  hist[(u32)t*NB1 + blockIdx.x] = h[t];
}

// ---------------- k_rpass: fused scan(hist) + scan(sums) + scatter + next-hist ----------------
__global__ void k_rpass(const u64* __restrict__ kin, u64* __restrict__ kout,
                        u32* __restrict__ hist, u32* __restrict__ histnext,
                        u32* __restrict__ sums, u32* __restrict__ cnt, u32* __restrict__ gen,
                        int shift) {
  __shared__ u32 lds[256];
  __shared__ u64 ball[4][8];
  __shared__ u64 vmask[4];
  int t = threadIdx.x, b = blockIdx.x;
  // phase A: blocks 0..292 scan their 1024-entry hist chunk; zero histnext chunk
  if (b < NBS) {
    int base = b*1024 + t*4;
    u32 v[4]; u32 tot = 0;
    for (int k = 0; k < 4; ++k) { v[k] = hist[base+k]; tot += v[k]; }
    lds[t] = tot; __syncthreads();
    for (int o = 1; o < 256; o <<= 1) {
      u32 x = (t >= o) ? lds[t-o] : 0u; __syncthreads();
      lds[t] += x; __syncthreads();
    }
    u32 excl = lds[t] - tot;
    if (t == 255) ASTR(&sums[b], lds[255]);
    u32 run = excl;
    for (int k = 0; k < 4; ++k) {
      ASTR(&hist[base+k], run);
      run += v[k];
      if (histnext) ASTR(&histnext[base+k], 0u);
    }
  }
  gridbar(cnt, gen, NB1);
  // phase B: block 0 scans the 293 chunk totals (512-slot two-half LDS scan)
  if (b == 0) {
    u32 a0 = (t < NBS) ? ALDR(&sums[t]) : 0u;
    u32 a1 = (256 + t < NBS) ? ALDR(&sums[256+t]) : 0u;
    lds[t] = a0; __syncthreads();
    for (int o = 1; o < 256; o <<= 1) {
      u32 x = (t >= o) ? lds[t-o] : 0u; __syncthreads();
      lds[t] += x; __syncthreads();
    }
    u32 incl0 = lds[t]; u32 tot0 = lds[255];
    if (t < NBS) ASTR(&sums[t], incl0 - a0);
    __syncthreads();
    lds[t] = a1; __syncthreads();
    for (int o = 1; o < 256; o <<= 1) {
      u32 x = (t >= o) ? lds[t-o] : 0u; __syncthreads();
      lds[t] += x; __syncthreads();
    }
    if (256 + t < NBS) ASTR(&sums[256+t], lds[t] - a1 + tot0);
  }
  gridbar(cnt, gen, NB1);
  // phase C: scatter + inline next-pass histogram
  int w = t >> 6, lane = t & 63;
  int i = b*256 + t;
  bool valid = i < K3F;
  u64 v = valid ? kin[i] : 0ull;
  u32 d = ((u32)(v >> 32) >> shift) & 255u;
  for (int bit = 0; bit < 8; ++bit) {
    u64 bm = __ballot(valid && ((d >> bit) & 1u));
    if (lane == 0) ball[w][bit] = bm;
  }
  u64 vb = __ballot(valid ? 1 : 0);
  if (lane == 0) vmask[w] = vb;
  __syncthreads();
  if (valid) {
    u32 rank = 0;
    for (int ww = 0; ww < w; ++ww) {
      u64 m = vmask[ww];
      for (int bit = 0; bit < 8; ++bit) { u64 bb = ball[ww][bit]; m &= ((d>>bit)&1u) ? bb : ~bb; }
      rank += (u32)__popcll(m);
    }
    u64 m = vmask[w];
    for (int bit = 0; bit < 8; ++bit) { u64 bb = ball[w][bit]; m &= ((d>>bit)&1u) ? bb : ~bb; }
    rank += (u32)__popcll(m & ((1ull<<lane)-1ull));
    u32 hh = d*(u32)NB1 + (u32)b;
    u32 pos = ALDR(&hist[hh]) + ALDR(&sums[hh>>10]) + rank;
    kout[pos] = v;
    if (histnext) {
      u32 d2 = ((u32)(v >> 32) >> (shift+8)) & 255u;
      atomicAdd(&histnext[d2*(u32)NB1 + (pos>>8)], 1u);
    }
  }
}

// ---------------- k_unique: flags + scan + unique/segoff/feid/ennode/xe, fused ----------------
__global__ void k_unique(const u64* __restrict__ kp, const float* __restrict__ x,
                         u32* __restrict__ bsum, u32* __restrict__ cnt, u32* __restrict__ gen,
                         u32* __restrict__ segoff, u32* __restrict__ feid,
                         float* __restrict__ xe, float* __restrict__ dout,
                         u32* __restrict__ scal, const int* __restrict__ divp) {
  __shared__ u32 lds[256];
  __shared__ u32 lastk[256];
  int t = threadIdx.x, b = blockIdx.x;
  int base = b*1024 + t*4;
  u64 kv[4];
  for (int k = 0; k < 4; ++k) {
    int p = base + k;
    kv[k] = (p < K3F) ? kp[p] : 0ull;
  }
  lastk[t] = (u32)(kv[3] >> 32);
  __syncthreads();
  u32 prevk;
  if (t == 0) prevk = (b == 0) ? 0u : (u32)(kp[b*1024 - 1] >> 32);
  else prevk = lastk[t-1];
  u32 fl[4]; u32 tot = 0;
  for (int k = 0; k < 4; ++k) {
    int p = base + k;
    u32 cur = (u32)(kv[k] >> 32);
    u32 prv = (k == 0) ? prevk : (u32)(kv[k-1] >> 32);
    u32 f = 0;
    if (p < K3F) f = (p == 0 || prv != cur) ? 1u : 0u;
    fl[k] = f; tot += f;
  }
  lds[t] = tot; __syncthreads();
  for (int o = 1; o < 256; o <<= 1) {
    u32 x2 = (t >= o) ? lds[t-o] : 0u; __syncthreads();
    lds[t] += x2; __syncthreads();
  }
  u32 excl = lds[t] - tot;
  if (t == 255) ASTR(&bsum[b], lds[255]);
  gridbar(cnt, gen, NBS);
  u32 partial = 0;
  for (int j = t; j < b; j += 256) partial += ALDR(&bsum[j]);
  __syncthreads();
  lds[t] = partial; __syncthreads();
  for (int o = 128; o; o >>= 1) { if (t < o) lds[t] += lds[t+o]; __syncthreads(); }
  u32 run = lds[0] + excl;
  for (int k = 0; k < 4; ++k) {
    int p = base + k;
    if (p >= K3F) break;
    u32 f = fl[k];
    u32 rk = run;
    u64 v = kv[k];
    u32 cur = (u32)(v >> 32);
    if (f) {
      u32 e = rk;
      segoff[e] = (u32)p;
      int kk32 = (int)(cur ^ 0x80000000u);
      long long kk = (long long)kk32;
      long long qq = (kk - (kk < 0 ? (long long)(VN-1) : 0ll)) / VN; // floor div
      int q = (int)qq;
      int r = (int)(kk - qq * VN);
      dout[2*e]   = (float)q;
      dout[2*e+1] = (float)r;
      u32 i0 = (u32)(q < 0 ? q + VN : q);  // numpy negative-index wrap
      u32 i1 = (u32)r;
      for (int c = 0; c < 3; ++c) xe[e*3+c] = 0.5f*(x[i0*3+c] + x[i1*3+c]);
    }
    u32 id = rk - 1u + f;
    u32 i = (u32)v;
    u32 s = i / FN, ff = i - s*FN;
    feid[ff*3 + s] = id;
    if (p == K3F-1) {
      u32 E = rk + f;
      u32 num = E / (u32)divp[0];
      scal[S_E] = E; scal[S_NUM] = num;
      segoff[E] = (u32)K3F;
      ASTR(&scal[S_PFX], 0u); ASTR(&scal[S_KREM], num);
    }
    run += f;
  }
}

// ---------------- neighbor aggregation from sort segments (bit-exact order) ----------------
__device__ __forceinline__ void agg_neighbors(int e, u32 st, u32 en,
                                              const u64* __restrict__ kp,
                                              const u32* __restrict__ feid,
                                              const float* __restrict__ v, int stride,
                                              float* acc0, float* acc1, float* acc2) {
  const int sslot[6] = {0,1,1,2,2,0};
  const int dslot[6] = {1,0,2,1,0,2};
  float c0 = 0.f, c1 = 0.f, c2 = 0.f;
  for (int b = 0; b < 6; ++b) {
    int j = dslot[b], isl = sslot[b];
    for (u32 p = st; p < en; ++p) {
      u32 i = (u32)kp[p];
      u32 s = i / FN;
      if ((int)s == j) {
        u32 f = i - s*FN;
        u32 u = feid[f*3 + isl];
        c0 += v[u*stride]; c1 += v[u*stride+1]; if (stride == 3) c2 += v[u*stride+2];
      }
    }
  }
  c0 += v[e*stride]; c1 += v[e*stride+1]; if (stride == 3) c2 += v[e*stride+2];
  *acc0 = c0; *acc1 = c1; *acc2 = c2;
}

// ---------------- k_l12: 2 edges per thread (ILP x2), scalar weights ----------------
__global__ void k_l12(const float* __restrict__ xe, const u32* __restrict__ segoff,
                      const u64* __restrict__ kp, const u32* __restrict__ feid,
                      const u32* __restrict__ scal, const float* __restrict__ pk,
                      float* __restrict__ P, float* __restrict__ Q) {
  int e1 = blockIdx.x*256 + threadIdx.x;
  int E = (int)scal[S_E];
  if (e1 >= E) return;
  int e2 = e1 + HALF1;
  bool v2 = e2 < E;
  int e2c = v2 ? e2 : e1;
  u32 st1 = segoff[e1], en1 = segoff[e1+1];
  u32 st2 = segoff[e2c], en2 = segoff[e2c+1];
  float c0a,c1a,c2a, c0b,c1b,c2b;
  agg_neighbors(e1,  st1, en1, kp, feid, xe, 3, &c0a,&c1a,&c2a);
  agg_neighbors(e2c, st2, en2, kp, feid, xe, 3, &c0b,&c1b,&c2b);
  float x0a=xe[e1*3],  x1a=xe[e1*3+1],  x2a=xe[e1*3+2];
  float x0b=xe[e2c*3], x1b=xe[e2c*3+1], x2b=xe[e2c*3+2];
  float dga = (float)(2u*(en1-st1)+1u), dgb = (float)(2u*(en2-st2)+1u);
  float m0a=c0a/dga, m1a=c1a/dga, m2a=c2a/dga;
  float m0b=c0b/dgb, m1b=c1b/dgb, m2b=c2b/dgb;
  float p0a=0,p1a=0,q0a=0,q1a=0, p0b=0,p1b=0,q0b=0,q1b=0;
#pragma unroll 4
  for (int hh = 0; hh < 256; ++hh) {
    const float* w = pk + hh*12;
    float w0=w[0],w1=w[1],w2=w[2],w3=w[3],w4=w[4],w5=w[5],w6=w[6];
    float w7=w[7],w8=w[8],w9=w[9],w10=w[10];
    float s1a = x0a*w0 + x1a*w1 + x2a*w2;
    float s2a = m0a*w3 + m1a*w4 + m2a*w5;
    float ha = fmaxf(s1a + s2a + w6, 0.0f);
    p0a += ha*w7;  p1a += ha*w8;  q0a += ha*w9;  q1a += ha*w10;
    float s1b = x0b*w0 + x1b*w1 + x2b*w2;
    float s2b = m0b*w3 + m1b*w4 + m2b*w5;
    float hb = fmaxf(s1b + s2b + w6, 0.0f);
    p0b += hb*w7;  p1b += hb*w8;  q0b += hb*w9;  q1b += hb*w10;
  }
  P[2*e1] = p0a; P[2*e1+1] = p1a; Q[2*e1] = q0a; Q[2*e1+1] = q1a;
  if (v2) { P[2*e2] = p0b; P[2*e2+1] = p1b; Q[2*e2] = q0b; Q[2*e2+1] = q1b; }
}

// ---------------- k_scores: 2 edges per thread ----------------
__device__ __forceinline__ void score_one(int e, const float* P, const float* Q,
                                          const u32* segoff, const u64* kp, const u32* feid,
                                          float b20, float b21, float* yo, u32* ymo) {
  u32 st = segoff[e], en = segoff[e+1];
  float a0, a1, dummy;
  agg_neighbors(e, st, en, kp, feid, Q, 2, &a0, &a1, &dummy);
  float dg = (float)(2u*(en - st) + 1u);
  float z0 = P[2*e]   + a0/dg + b20;
  float z1 = P[2*e+1] + a1/dg + b21;
  float l0 = 1.0f/(1.0f + expf(-z0));
  float l1 = 1.0f/(1.0f + expf(-z1));
  u32 g0b, g1b;
  { u32 o0,o1; tf2x32(0u, 2u*(u32)e,      o0, o1); g0b = o0 ^ o1; }
  { u32 o0,o1; tf2x32(0u, 2u*(u32)e + 1u, o0, o1); g1b = o0 ^ o1; }
  float U0 = __uint_as_float((g0b>>9) | 0x3f800000u) - 1.0f;
  float U1 = __uint_as_float((g1b>>9) | 0x3f800000u) - 1.0f;
  float g0 = -logf(-logf(U0 + 1e-20f) + 1e-20f);
  float g1 = -logf(-logf(U1 + 1e-20f) + 1e-20f);
  float A0 = (l0 + g0)/0.1f;
  float A1 = (l1 + g1)/0.1f;
  float mx = fmaxf(A0, A1);
  float e0 = expf(A0-mx), e1v = expf(A1-mx);
  float y = e0/(e0+e1v);
  *yo = y;
  *ymo = __float_as_uint(y) | 0x80000000u;
}

__global__ void k_scores(const float* __restrict__ P, const float* __restrict__ Q,
                         const u32* __restrict__ segoff, const u64* __restrict__ kp,
                         const u32* __restrict__ feid,
                         const float* __restrict__ b2, const u32* __restrict__ scal,
                         float* __restrict__ Y, u32* __restrict__ ymap) {
  int e1 = blockIdx.x*256 + threadIdx.x;
  int E = (int)scal[S_E];
  if (e1 >= E) return;
  int e2 = e1 + HALF1;
  bool v2 = e2 < E;
  int e2c = v2 ? e2 : e1;
  float b20 = b2[0], b21 = b2[1];
  float ya, yb; u32 ma, mb;
  score_one(e1,  P, Q, segoff, kp, feid, b20, b21, &ya, &ma);
  score_one(e2c, P, Q, segoff, kp, feid, b20, b21, &yb, &mb);
  Y[e1] = ya; ymap[e1] = ma;
  if (v2) { Y[e2] = yb; ymap[e2] = mb; }
}

// ---------------- k_topk: 4 byte-rounds + packed scan + sel/selr, one kernel ----------------
__global__ void k_topk(const u32* __restrict__ ymap, u32* __restrict__ scal,
                       u32* __restrict__ tkh, u32* __restrict__ cnt, u32* __restrict__ gen,
                       u64* __restrict__ sums64,
                       u32* __restrict__ sel, u32* __restrict__ selr) {
  __shared__ u32 h[256];
  __shared__ u64 l64[256];
  __shared__ u32 chosen_s;
  int t = threadIdx.x, b = blockIdx.x;
  int base = b*1024 + t*4;
  int E = (int)scal[S_E];
  u32 ym[4]; bool val[4];
  for (int k = 0; k < 4; ++k) {
    int e = base + k;
    val[k] = e < E;
    ym[k] = val[k] ? ymap[e] : 0u;
  }
  u32 pfx = 0u;
  for (int byte = 3; byte >= 0; --byte) {
    h[t] = 0u;
    __syncthreads();
    for (int k = 0; k < 4; ++k) {
      if (val[k]) {
        bool match = (byte == 3) || ((ym[k] >> ((byte+1)*8)) == pfx);
        if (match) atomicAdd(&h[(ym[k] >> (byte*8)) & 255u], 1u);
      }
    }
    __syncthreads();
    if (h[t]) atomicAdd(&tkh[t], h[t]);
    gridbar(cnt, gen, NBH);
    if (b == 0) {
      u32 v = ALDR(&tkh[t]);
      ASTR(&tkh[t], 0u);
      h[t] = v;
      if (t == 0) chosen_s = 0u;
      __syncthreads();
      for (int o = 1; o < 256; o <<= 1) {
        u32 x2 = (t + o < 256) ? h[t+o] : 0u; __syncthreads();
        h[t] += x2; __syncthreads();
      }
      u32 krem = ALDR(&scal[S_KREM]);
      if (h[t] >= krem) atomicMax(&chosen_s, (u32)t);
      __syncthreads();
      if (t == 0) {
        u32 chosen = chosen_s;
        u32 sufnext = (chosen < 255u) ? h[chosen+1] : 0u;
        u32 newkrem = krem - sufnext;
        u32 npfx = (pfx << 8) | chosen;
        ASTR(&scal[S_PFX], npfx);
        ASTR(&scal[S_KREM], newkrem);
        if (byte == 0) { ASTR(&scal[S_TU], npfx); ASTR(&scal[S_R], newkrem); }
      }
    }
    gridbar(cnt, gen, NBH);
    pfx = ALDR(&scal[S_PFX]);
  }
  // selection scan: gt in lo32, tie in hi32
  u32 TU = ALDR(&scal[S_TU]), R = ALDR(&scal[S_R]);
  u64 vv[4]; u64 tot = 0;
  for (int k = 0; k < 4; ++k) {
    u64 x2 = 0;
    if (val[k]) {
      if (ym[k] > TU) x2 = 1ull;
      else if (ym[k] == TU) x2 = 1ull << 32;
    }
    vv[k] = x2; tot += x2;
  }
  l64[t] = tot; __syncthreads();
  for (int o = 1; o < 256; o <<= 1) {
    u64 x2 = (t >= o) ? l64[t-o] : 0ull; __syncthreads();
    l64[t] += x2; __syncthreads();
  }
  u64 excl = l64[t] - tot;
  if (t == 255) ASTR(&sums64[b], l64[255]);
  gridbar(cnt, gen, NBH);
  u64 partial = 0;
  for (int j = t; j < b; j += 256) partial += ALDR(&sums64[j]);
  __syncthreads();
  l64[t] = partial; __syncthreads();
  for (int o = 128; o; o >>= 1) { if (t < o) l64[t] += l64[t+o]; __syncthreads(); }
  u64 run = l64[0] + excl;
  for (int k = 0; k < 4; ++k) {
    int e = base + k;
    if (e < EMAX) {
      u32 GTpre = (u32)run, TIEpre = (u32)(run >> 32);
      u32 v = 0;
      if (val[k]) v = (ym[k] > TU) || (ym[k] == TU && TIEpre < R);
      sel[e] = v ? 1u : 0u;
      selr[e] = GTpre + min(TIEpre, R);
    }
    run += vv[k];
  }
}

// ---------------- mesh collapse ----------------
__global__ void k_catfused(const u32* __restrict__ feid, const u32* __restrict__ sel,
                           u32* __restrict__ cat, u32* __restrict__ ch) {
  __shared__ u32 h[8];
  int t = threadIdx.x;
  if (t < 8) h[t] = 0u;
  __syncthreads();
  int base = blockIdx.x*1024 + t*4;
  for (int k = 0; k < 4; ++k) {
    int f = base + k;
    if (f < FN) {
      u32 m0 = sel[feid[f*3]], m1 = sel[feid[f*3+1]], m2 = sel[feid[f*3+2]];
      u32 pen = m0 + m1 + m2;
      u32 psi = m1 + 2u*m2;
      u32 c = (pen == 0) ? 0u : (pen == 1) ? (1u+psi) : (pen == 2) ? (3u+psi) : 7u;
      cat[f] = c;
      atomicAdd(&h[c], 1u);
    }
  }
  __syncthreads();
  if (t < 8) ch[(u32)t*NBC + blockIdx.x] = h[t];
}

__global__ void k_catoff(u32* __restrict__ ch, u32* __restrict__ scal) {
  __shared__ u32 lds[256];
  __shared__ u32 ex[1024];
  int t = threadIdx.x;
  u32 v[4]; u32 tot = 0;
  for (int k = 0; k < 4; ++k) {
    int i = t*4 + k;
    u32 x = (i < 8*NBC) ? ch[i] : 0u;
    v[k] = x; tot += x;
  }
  lds[t] = tot; __syncthreads();
  for (int o = 1; o < 256; o <<= 1) {
    u32 x = (t >= o) ? lds[t-o] : 0u; __syncthreads();
    lds[t] += x; __syncthreads();
  }
  u32 excl = lds[t] - tot;
  u32 run = excl;
  for (int k = 0; k < 4; ++k) { ex[t*4+k] = run; run += v[k]; }
  __syncthreads();
  for (int k = 0; k < 4; ++k) {
    int i = t*4 + k;
    if (i < 8*NBC) ch[i] = ex[i];
  }
  if (t == 0) {
    u32 total = lds[255];
    u32 bnd[9];
    for (int c = 0; c < 8; ++c) bnd[c] = ex[c*NBC];
    bnd[8] = total;
    u32 tot8[8];
    for (int c = 0; c < 8; ++c) tot8[c] = bnd[c+1] - bnd[c];
    u32 n0 = tot8[0], n1 = tot8[1]+tot8[2]+tot8[3], n2 = tot8[4]+tot8[5]+tot8[6], n3 = tot8[7];
    u32 NF = n0 + 2u*n1 + 3u*n2 + 4u*n3;
    u32 E = scal[S_E], num = scal[S_NUM];
    u32 NEn = (u32)VN + num + 3u*NF;
    scal[S_NF] = NF; scal[S_NEN] = NEn;
    scal[S_O1] = 2u*E;
    scal[S_O2] = 2u*E + 3u*NF;
    scal[S_O3] = 2u*E + 3u*NF + 2u*NEn;
    u32 RS[8] = {0u, n0,n0,n0, n0+2u*n1, n0+2u*n1, n0+2u*n1, n0+2u*n1+3u*n2};
    u32 GS[8] = {0u, n1,n1,n1, n2,n2,n2, n3};
    u32 GP[8] = {0u, n0,n0,n0, n0+n1, n0+n1, n0+n1, n0+n1+n2};
    for (int i = 0; i < 8; ++i) { scal[S_RS+i] = RS[i]; scal[S_GS+i] = GS[i]; scal[S_GP+i] = GP[i]; }
  }
}

__global__ void k_catrank(const u32* __restrict__ cat, const u32* __restrict__ ch,
                          u32* __restrict__ cr) {
  __shared__ u32 lds[256];
  int t = threadIdx.x;
  int base = blockIdx.x*1024 + t*4;
  u32 cc[4], loc[4];
  u32 cnt[8] = {0,0,0,0,0,0,0,0};
  for (int k = 0; k < 4; ++k) {
    int i = base + k;
    if (i < FN) { u32 c = cat[i]; cc[k] = c; loc[k] = cnt[c]++; }
    else cc[k] = 8u;
  }
  u32 tb[8];
  for (int c = 0; c < 8; ++c) {
    lds[t] = cnt[c]; __syncthreads();
    for (int o = 1; o < 256; o <<= 1) {
      u32 x = (t >= o) ? lds[t-o] : 0u; __syncthreads();
      lds[t] += x; __syncthreads();
    }
    tb[c] = lds[t] - cnt[c];
    __syncthreads();
  }
  for (int k = 0; k < 4; ++k) {
    int i = base + k;
    if (i < FN) { u32 c = cc[k]; cr[i] = ch[c*NBC + blockIdx.x] + tb[c] + loc[k]; }
  }
}

__global__ void k_wfaces(const int* __restrict__ face, const u32* __restrict__ cat,
                         const u32* __restrict__ cr, const u32* __restrict__ feid,
                         const u32* __restrict__ selr, const u32* __restrict__ scal,
                         int* __restrict__ nfi, float* __restrict__ dout) {
  int f = blockIdx.x*256 + threadIdx.x;
  if (f >= FN) return;
  const int nfc[8] = {1,2,2,2,3,3,3,4};
  const int tri[8][4][3] = {
    {{0,2,4},{0,0,0},{0,0,0},{0,0,0}},
    {{0,1,4},{1,2,4},{0,0,0},{0,0,0}},
    {{2,3,0},{3,4,0},{0,0,0},{0,0,0}},
    {{4,5,2},{5,0,2},{0,0,0},{0,0,0}},
    {{0,1,4},{1,2,3},{1,3,4},{0,0,0}},
    {{4,5,2},{5,0,1},{5,1,2},{0,0,0}},
    {{2,3,0},{3,4,5},{3,5,0},{0,0,0}},
    {{0,1,5},{1,2,3},{1,3,5},{3,4,5}}};
  u32 c = cat[f];
  int cv[6];
  cv[0] = face[f*3];   cv[2] = face[f*3+1]; cv[4] = face[f*3+2];
  cv[1] = VN + (int)selr[feid[f*3]];
  cv[3] = VN + (int)selr[feid[f*3+1]];
  cv[5] = VN + (int)selr[feid[f*3+2]];
  u32 g  = cr[f] - scal[S_GP + c];
  u32 o1 = scal[S_O1];
  for (int j = 0; j < nfc[c]; ++j) {
    u32 row = scal[S_RS + c] + (u32)j*scal[S_GS + c] + g;
    for (int m = 0; m < 3; ++m) {
      int v = cv[tri[c][j][m]];
      nfi[row*3 + m] = v;
      dout[o1 + row*3 + m] = (float)v;
    }
  }
}

__global__ void k_wne(const int* __restrict__ nfi, const u32* __restrict__ scal,
                      float* __restrict__ dout) {
  int i = blockIdx.x*256 + threadIdx.x;
  u32 NEn = scal[S_NEN];
  if (i >= (int)NEn) return;
  u32 NF = scal[S_NF];
  u32 Vp = (u32)VN + scal[S_NUM];
  u32 o2 = scal[S_O2];
  int a, b;
  if ((u32)i < Vp) { a = i; b = i; }
  else {
    u32 j = (u32)i - Vp;
    u32 blk = j / NF, r = j - blk*NF;
    int i0 = (blk == 0) ? 0 : (blk == 1) ? 1 : 2;
    int i1 = (blk == 0) ? 1 : (blk == 1) ? 2 : 0;
    a = nfi[r*3 + i0]; b = nfi[r*3 + i1];
  }
  dout[o2 + i] = (float)a;
  dout[o2 + NEn + i] = (float)b;
}

__global__ void k_wmask(const u32* __restrict__ sel, const float* __restrict__ Y,
                        const u32* __restrict__ scal, float* __restrict__ dout) {
  int e = blockIdx.x*256 + threadIdx.x;
  if (e >= (int)scal[S_E]) return;
  float y = Y[e];
  float yh = sel[e] ? 1.0f : 0.0f;
  dout[scal[S_O3] + e] = (yh - y) + y;
}

extern "C" void kernel_launch(void* const* d_in, const int* in_sizes, int n_in,
                              void* d_out, int out_size, void* d_ws, size_t ws_size,
                              hipStream_t stream) {
  const float* x    = (const float*)d_in[0];
  const int*   face = (const int*)d_in[1];
  const int*   divp = (const int*)d_in[4];
  const float* W1s  = (const float*)d_in[5];
  const float* W1n  = (const float*)d_in[6];
  const float* b1   = (const float*)d_in[7];
  const float* W2s  = (const float*)d_in[8];
  const float* W2n  = (const float*)d_in[9];
  const float* b2   = (const float*)d_in[10];
  float* out = (float*)d_out;
  u32* W = (u32*)d_ws;

  u64 *KPA = (u64*)(W+W_KPA), *KPB = (u64*)(W+W_KPB);
  u32 *HIST = W+W_HIST, *HIST2 = W+W_HIST2, *SUMS = W+W_SUMS, *SCAL = W+W_SCAL;
  u32 *TKH = W+W_TKH, *DONE = W+W_DONE;
  u64 *SUMS64 = (u64*)(W+W_SUMS);

  // 1) keys + 4 fused radix passes (each: scan+scan+scatter+next-hist in one dispatch)
  k_keys<<<NB1, 256, 0, stream>>>(face, W1s, W1n, b1, W2s, W2n, (float*)(W+W_PK),
                                  KPA, HIST, TKH, DONE);
  k_rpass<<<NB1, 256, 0, stream>>>(KPA, KPB, HIST,  HIST2, SUMS, DONE+0, DONE+1,  0);
  k_rpass<<<NB1, 256, 0, stream>>>(KPB, KPA, HIST2, HIST,  SUMS, DONE+0, DONE+1,  8);
  k_rpass<<<NB1, 256, 0, stream>>>(KPA, KPB, HIST,  HIST2, SUMS, DONE+0, DONE+1, 16);
  k_rpass<<<NB1, 256, 0, stream>>>(KPB, KPA, HIST2, nullptr, SUMS, DONE+0, DONE+1, 24);

  // 2) unique + segoff + feid + edge-node outputs + xe, one dispatch
  k_unique<<<NBS, 256, 0, stream>>>(KPA, x, SUMS, DONE+2, DONE+3,
                                    W+W_SEGOFF, W+W_FEID, (float*)(W+W_XE), out, SCAL, divp);

  // 3) GSN conv layers (thread handles 2 edges for ILP)
  k_l12<<<NBL, 256, 0, stream>>>((float*)(W+W_XE), W+W_SEGOFF, KPA, W+W_FEID, SCAL,
                                 (float*)(W+W_PK), (float*)(W+W_P), (float*)(W+W_Q));
  k_scores<<<NBL, 256, 0, stream>>>((float*)(W+W_P), (float*)(W+W_Q), W+W_SEGOFF, KPA,
                                    W+W_FEID, b2, SCAL, (float*)(W+W_Y), W+W_YMAP);

  // 4) top-k + selection, one dispatch
  k_topk<<<NBH, 256, 0, stream>>>(W+W_YMAP, SCAL, TKH, DONE+4, DONE+5, SUMS64,
                                  W+W_SEL, W+W_SELR);

  // 5) mesh collapse
  k_catfused<<<NBC, 256, 0, stream>>>(W+W_FEID, W+W_SEL, W+W_CAT, W+W_CATH);
  k_catoff<<<1, 256, 0, stream>>>(W+W_CATH, SCAL);
  k_catrank<<<NBC, 256, 0, stream>>>(W+W_CAT, W+W_CATH, W+W_CATR);
  k_wfaces<<<391, 256, 0, stream>>>(face, W+W_CAT, W+W_CATR, W+W_FEID, W+W_SELR, SCAL,
                                    (int*)(W+W_NFI), out);
  k_wne<<<5118, 256, 0, stream>>>((int*)(W+W_NFI), SCAL, out);
  k_wmask<<<NB1, 256, 0, stream>>>(W+W_SEL, (float*)(W+W_Y), SCAL, out);
}

// Round 8
// 343.738 us; speedup vs baseline: 4.0219x; 4.0219x over previous
//
#include <hip/hip_runtime.h>
#include <stdint.h>

typedef uint32_t u32;
typedef uint64_t u64;

#define VN 50000
#define FN 100000
#define K3F 300000
#define EMAX 300000
#define NB1 1172          // ceil(300000/256); NB1*256 = 300032
#define NBS 293           // 293*1024 = 300032
#define NBH 293
#define NBC 98            // ceil(100000/1024)
#define HALF1 150016      // 586*256
#define NBL 586

// ---------------- workspace layout (u32 units) ----------------
#define W_KPA    0u        // 600000 (300000 u64) ping
#define W_KPB    600000u   // 600000 pong
#define W_SEGOFF 1200000u  // 300001
#define W_FEID   1500004u  // 300000
#define W_XE     1800004u  // 900000 f32
#define W_PK     2700004u  // 3072 f32 packed weights
#define W_P      2703076u  // 600000 f32
#define W_Q      3303076u  // 600000 f32
#define W_Y      3903076u  // 300000 f32
#define W_YMAP   4203076u  // 300000
#define W_T64    4503076u  // 600064 (u64 region; offset even -> 8B aligned; also rank tmp)
#define W_SEL    5103140u  // 300000
#define W_SELR   5403140u  // 300000
#define W_CAT    5703140u  // 100000
#define W_CATR   5803140u  // 100000
#define W_NFI    5903140u  // 1200000 int
#define W_HIST   7103140u  // 300032
#define W_HIST2  7403172u  // 300032
#define W_SUMS   7703204u  // 4096 (even -> u64-reusable)
#define W_CATH   7707300u  // 1024
#define W_TKH    7708324u  // 256
#define W_DONE   7708580u  // 32
#define W_SCAL   7708612u  // 64

#define S_E 0
#define S_NUM 1
#define S_PFX 2
#define S_KREM 3
#define S_TU 4
#define S_R 5
#define S_NF 6
#define S_NEN 7
#define S_O1 8
#define S_O2 9
#define S_O3 10
#define S_RS 16
#define S_GS 24
#define S_GP 32

// ---------------- threefry2x32, key = (0, 42) ----------------
__device__ __forceinline__ void tf2x32(u32 x0, u32 x1, u32& o0, u32& o1) {
  const u32 ks0 = 0u, ks1 = 42u, ks2 = 0x1BD11BDAu ^ 0u ^ 42u;
  x0 += ks0; x1 += ks1;
#define TFR(r) { x0 += x1; x1 = (x1<<(r))|(x1>>(32-(r))); x1 ^= x0; }
  TFR(13) TFR(15) TFR(26) TFR(6)   x0 += ks1; x1 += ks2 + 1u;
  TFR(17) TFR(29) TFR(16) TFR(24)  x0 += ks2; x1 += ks0 + 2u;
  TFR(13) TFR(15) TFR(26) TFR(6)   x0 += ks0; x1 += ks1 + 3u;
  TFR(17) TFR(29) TFR(16) TFR(24)  x0 += ks1; x1 += ks2 + 4u;
  TFR(13) TFR(15) TFR(26) TFR(6)   x0 += ks2; x1 += ks0 + 5u;
#undef TFR
  o0 = x0; o1 = x1;
}

// ---------------- scans (u32) + next-hist zeroing ----------------
__global__ void scan_blocks(const u32* __restrict__ in, u32* __restrict__ out,
                            u32* __restrict__ sums, int n, u32* __restrict__ zeronext) {
  __shared__ u32 lds[256];
  int t = threadIdx.x;
  int base = blockIdx.x*1024 + t*4;
  u32 v[4]; u32 tot = 0;
  for (int k = 0; k < 4; ++k) { v[k] = (base+k < n) ? in[base+k] : 0u; tot += v[k]; }
  lds[t] = tot; __syncthreads();
  for (int o = 1; o < 256; o <<= 1) {
    u32 x = (t >= o) ? lds[t-o] : 0u; __syncthreads();
    lds[t] += x; __syncthreads();
  }
  u32 excl = lds[t] - tot;
  if (t == 255) sums[blockIdx.x] = lds[255];
  u32 run = excl;
  for (int k = 0; k < 4; ++k) {
    if (base+k < n) {
      out[base+k] = run;
      if (zeronext) zeronext[base+k] = 0u;
    }
    run += v[k];
  }
}

__global__ void scan_flagblocks(const u64* __restrict__ kp, u32* __restrict__ out,
                                u32* __restrict__ sums, int n) {
  __shared__ u32 lds[256];
  int t = threadIdx.x;
  int base = blockIdx.x*1024 + t*4;
  u32 v[4]; u32 tot = 0;
  for (int k = 0; k < 4; ++k) {
    int i = base + k;
    u32 f = 0;
    if (i < n) f = (i == 0 || (u32)(kp[i-1]>>32) != (u32)(kp[i]>>32)) ? 1u : 0u;
    v[k] = f; tot += f;
  }
  lds[t] = tot; __syncthreads();
  for (int o = 1; o < 256; o <<= 1) {
    u32 x = (t >= o) ? lds[t-o] : 0u; __syncthreads();
    lds[t] += x; __syncthreads();
  }
  u32 excl = lds[t] - tot;
  if (t == 255) sums[blockIdx.x] = lds[255];
  u32 run = excl;
  for (int k = 0; k < 4; ++k) { if (base+k < n) out[base+k] = run; run += v[k]; }
}

__global__ void scan_sums(u32* __restrict__ s, int nb) {
  __shared__ u32 lds[256];
  __shared__ u32 carry;
  int t = threadIdx.x;
  if (t == 0) carry = 0;
  __syncthreads();
  for (int base = 0; base < nb; base += 1024) {
    int idx = base + t*4;
    u32 v[4]; u32 tot = 0;
    for (int k = 0; k < 4; ++k) { v[k] = (idx+k < nb) ? s[idx+k] : 0u; tot += v[k]; }
    lds[t] = tot; __syncthreads();
    for (int o = 1; o < 256; o <<= 1) {
      u32 x = (t >= o) ? lds[t-o] : 0u; __syncthreads();
      lds[t] += x; __syncthreads();
    }
    u32 excl = lds[t] - tot;
    u32 ctot = lds[255];
    u32 c = carry;
    __syncthreads();
    u32 run = c + excl;
    for (int k = 0; k < 4; ++k) { if (idx+k < nb) s[idx+k] = run; run += v[k]; }
    if (t == 0) carry = c + ctot;
    __syncthreads();
  }
}

// ---------------- u64 packed scan (gt lo32, tie hi32) ----------------
__global__ void scan64_src(const u32* __restrict__ ymap, const u32* __restrict__ scal,
                           u64* __restrict__ part, u64* __restrict__ sums) {
  __shared__ u64 lds[256];
  int t = threadIdx.x;
  int base = blockIdx.x*1024 + t*4;
  int E = (int)scal[S_E];
  u32 TU = scal[S_TU];
  u64 v[4]; u64 tot = 0;
  for (int k = 0; k < 4; ++k) {
    int e = base + k;
    u64 val = 0;
    if (e < E) {
      u32 u = ymap[e];
      if (u > TU) val = 1ull;
      else if (u == TU) val = 1ull << 32;
    }
    v[k] = val; tot += val;
  }
  lds[t] = tot; __syncthreads();
  for (int o = 1; o < 256; o <<= 1) {
    u64 x = (t >= o) ? lds[t-o] : 0ull; __syncthreads();
    lds[t] += x; __syncthreads();
  }
  u64 excl = lds[t] - tot;
  if (t == 255) sums[blockIdx.x] = lds[255];
  u64 run = excl;
  for (int k = 0; k < 4; ++k) { part[base+k] = run; run += v[k]; }
}

__global__ void scan64_sums(u64* __restrict__ s, int nb) {
  __shared__ u64 lds[256];
  int t = threadIdx.x;
  int idx = t*4;
  u64 v[4]; u64 tot = 0;
  for (int k = 0; k < 4; ++k) { v[k] = (idx+k < nb) ? s[idx+k] : 0ull; tot += v[k]; }
  lds[t] = tot; __syncthreads();
  for (int o = 1; o < 256; o <<= 1) {
    u64 x = (t >= o) ? lds[t-o] : 0ull; __syncthreads();
    lds[t] += x; __syncthreads();
  }
  u64 excl = lds[t] - tot;
  u64 run = excl;
  for (int k = 0; k < 4; ++k) { if (idx+k < nb) s[idx+k] = run; run += v[k]; }
}

__global__ void k_sel2(const u32* __restrict__ ymap, const u64* __restrict__ part,
                       const u64* __restrict__ sums, const u32* __restrict__ scal,
                       u32* __restrict__ sel, u32* __restrict__ selr) {
  int e = blockIdx.x*256 + threadIdx.x;
  if (e >= EMAX) return;
  int E = (int)scal[S_E];
  u32 TU = scal[S_TU], R = scal[S_R];
  u64 pre = part[e] + sums[e>>10];
  u32 GTpre = (u32)pre, TIEpre = (u32)(pre >> 32);
  u32 v = 0;
  if (e < E) {
    u32 u = ymap[e];
    v = (u > TU) || (u == TU && TIEpre < R);
  }
  sel[e] = v ? 1u : 0u;
  selr[e] = GTpre + min(TIEpre, R);
}

// ---------------- radix scatter (u64, key hi32) + inline next-pass histogram ----------------
__global__ void k_rscat(const u64* __restrict__ kp, u64* __restrict__ okp,
                        const u32* __restrict__ hist, const u32* __restrict__ sums,
                        int shift, int nb, u32* __restrict__ histnext) {
  __shared__ u64 ball[4][8];
  __shared__ u64 vmask[4];
  int t = threadIdx.x, w = t>>6, lane = t&63;
  int i = blockIdx.x*256 + t;
  bool valid = i < K3F;
  u64 v = valid ? kp[i] : 0ull;
  u32 d = ((u32)(v>>32) >> shift) & 255u;
  for (int bit = 0; bit < 8; ++bit) {
    u64 bm = __ballot(valid && ((d>>bit)&1u));
    if (lane == 0) ball[w][bit] = bm;
  }
  u64 vb = __ballot(valid ? 1 : 0);
  if (lane == 0) vmask[w] = vb;
  __syncthreads();
  if (valid) {
    u32 rank = 0;
    for (int ww = 0; ww < w; ++ww) {
      u64 m = vmask[ww];
      for (int bit = 0; bit < 8; ++bit) { u64 bb = ball[ww][bit]; m &= ((d>>bit)&1u) ? bb : ~bb; }
      rank += (u32)__popcll(m);
    }
    u64 m = vmask[w];
    for (int bit = 0; bit < 8; ++bit) { u64 bb = ball[w][bit]; m &= ((d>>bit)&1u) ? bb : ~bb; }
    rank += (u32)__popcll(m & ((1ull<<lane)-1ull));
    u32 h = d*(u32)nb + blockIdx.x;
    u32 pos = hist[h] + sums[h>>10] + rank;
    okp[pos] = v;
    if (histnext) {
      u32 d2 = ((u32)(v>>32) >> (shift+8)) & 255u;
      atomicAdd(&histnext[d2*(u32)nb + (pos>>8)], 1u);
    }
  }
}

// ---------------- pipeline kernels ----------------
__global__ void k_keys(const int* __restrict__ face,
                       const float* __restrict__ W1s, const float* __restrict__ W1n,
                       const float* __restrict__ b1,
                       const float* __restrict__ W2s, const float* __restrict__ W2n,
                       float* __restrict__ pk,
                       u64* __restrict__ kp, u32* __restrict__ hist,
                       u32* __restrict__ tkh, u32* __restrict__ done) {
  __shared__ u32 h[256];
  int t = threadIdx.x;
  h[t] = 0;
  __syncthreads();
  if (blockIdx.x == 0) {
    tkh[t] = 0u;
    if (t < 32) done[t] = 0u;
    float* p = pk + t*12;
    p[0] = W1s[t]; p[1] = W1s[256+t]; p[2] = W1s[512+t];
    p[3] = W1n[t]; p[4] = W1n[256+t]; p[5] = W1n[512+t];
    p[6] = b1[t];
    p[7] = W2s[2*t]; p[8] = W2s[2*t+1];
    p[9] = W2n[2*t]; p[10] = W2n[2*t+1];
    p[11] = 0.0f;
  }
  int i = blockIdx.x*256 + t;
  if (i < K3F) {
    int s = i / FN, f = i - s*FN;
    int v0 = face[f*3 + s];
    int v1 = face[f*3 + (s == 2 ? 0 : s+1)];
    int a = min(v0, v1), b = max(v0, v1);
    u32 key = ((u32)a * (u32)VN + (u32)b) ^ 0x80000000u;  // biased int32-wrap key
    kp[i] = ((u64)key << 32) | (u32)i;                     // payload = orig index
    atomicAdd(&h[key & 255u], 1u);
  }
  __syncthreads();
  hist[(u32)t*NB1 + blockIdx.x] = h[t];
}

// unique segments + feid scatter + edge-node outputs + xe gather + tk init, fused
__global__ void k_uwrite(const u64* __restrict__ kp, const u32* __restrict__ rankp,
                         const u32* __restrict__ sums, const float* __restrict__ x,
                         u32* __restrict__ segoff, u32* __restrict__ feid,
                         float* __restrict__ xe, float* __restrict__ dout,
                         u32* __restrict__ scal, const int* __restrict__ divp) {
  int p = blockIdx.x*256 + threadIdx.x;
  if (p >= K3F) return;
  u64 v = kp[p];
  u32 cur = (u32)(v >> 32);
  u32 fl = (p == 0 || (u32)(kp[p-1] >> 32) != cur) ? 1u : 0u;
  u32 rk = rankp[p] + sums[p>>10];
  if (fl) {
    u32 e = rk;
    segoff[e] = (u32)p;
    int k = (int)(cur ^ 0x80000000u);
    long long kk = (long long)k;
    long long qq = (kk - (kk < 0 ? (long long)(VN-1) : 0ll)) / VN; // floor div
    int q = (int)qq;
    int r = (int)(kk - qq * VN);
    dout[2*e]   = (float)q;
    dout[2*e+1] = (float)r;
    u32 i0 = (u32)(q < 0 ? q + VN : q);  // numpy negative-index wrap
    u32 i1 = (u32)r;
    for (int c = 0; c < 3; ++c) xe[e*3+c] = 0.5f*(x[i0*3+c] + x[i1*3+c]);
  }
  u32 id = rk - 1u + fl;
  u32 i = (u32)v;
  u32 s = i / FN, f = i - s*FN;
  feid[f*3 + s] = id;
  if (p == K3F-1) {
    u32 E = rk + fl;
    u32 num = E / (u32)divp[0];
    scal[S_E] = E; scal[S_NUM] = num;
    segoff[E] = (u32)K3F;
    scal[S_PFX] = 0u; scal[S_KREM] = num;   // top-k init (fused)
  }
}

// Neighbor aggregation direct from key-sort segments (bit-exact reference order).
__device__ __forceinline__ void agg_neighbors(int e, u32 st, u32 en,
                                              const u64* __restrict__ kp,
                                              const u32* __restrict__ feid,
                                              const float* __restrict__ v, int stride,
                                              float* acc0, float* acc1, float* acc2) {
  const int sslot[6] = {0,1,1,2,2,0};
  const int dslot[6] = {1,0,2,1,0,2};
  float c0 = 0.f, c1 = 0.f, c2 = 0.f;
  for (int b = 0; b < 6; ++b) {
    int j = dslot[b], isl = sslot[b];
    for (u32 p = st; p < en; ++p) {
      u32 i = (u32)kp[p];
      u32 s = i / FN;
      if ((int)s == j) {
        u32 f = i - s*FN;
        u32 u = feid[f*3 + isl];
        c0 += v[u*stride]; c1 += v[u*stride+1]; if (stride == 3) c2 += v[u*stride+2];
      }
    }
  }
  c0 += v[e*stride]; c1 += v[e*stride+1]; if (stride == 3) c2 += v[e*stride+2];
  *acc0 = c0; *acc1 = c1; *acc2 = c2;
}

// fused neighbor-mean + layer1 + projection, 2 edges/thread (ILP), scalar weights
__global__ void k_l12(const float* __restrict__ xe, const u32* __restrict__ segoff,
                      const u64* __restrict__ kp, const u32* __restrict__ feid,
                      const u32* __restrict__ scal, const float* __restrict__ pk,
                      float* __restrict__ P, float* __restrict__ Q) {
  int e1 = blockIdx.x*256 + threadIdx.x;
  int E = (int)scal[S_E];
  if (e1 >= E) return;
  int e2 = e1 + HALF1;
  bool v2 = e2 < E;
  int e2c = v2 ? e2 : e1;
  u32 st1 = segoff[e1], en1 = segoff[e1+1];
  u32 st2 = segoff[e2c], en2 = segoff[e2c+1];
  float c0a,c1a,c2a, c0b,c1b,c2b;
  agg_neighbors(e1,  st1, en1, kp, feid, xe, 3, &c0a,&c1a,&c2a);
  agg_neighbors(e2c, st2, en2, kp, feid, xe, 3, &c0b,&c1b,&c2b);
  float x0a=xe[e1*3],  x1a=xe[e1*3+1],  x2a=xe[e1*3+2];
  float x0b=xe[e2c*3], x1b=xe[e2c*3+1], x2b=xe[e2c*3+2];
  float dga = (float)(2u*(en1-st1)+1u), dgb = (float)(2u*(en2-st2)+1u);
  float m0a=c0a/dga, m1a=c1a/dga, m2a=c2a/dga;
  float m0b=c0b/dgb, m1b=c1b/dgb, m2b=c2b/dgb;
  float p0a=0,p1a=0,q0a=0,q1a=0, p0b=0,p1b=0,q0b=0,q1b=0;
#pragma unroll 4
  for (int hh = 0; hh < 256; ++hh) {
    const float* w = pk + hh*12;
    float w0=w[0],w1=w[1],w2=w[2],w3=w[3],w4=w[4],w5=w[5],w6=w[6];
    float w7=w[7],w8=w[8],w9=w[9],w10=w[10];
    float s1a = x0a*w0 + x1a*w1 + x2a*w2;
    float s2a = m0a*w3 + m1a*w4 + m2a*w5;
    float ha = fmaxf(s1a + s2a + w6, 0.0f);
    p0a += ha*w7;  p1a += ha*w8;  q0a += ha*w9;  q1a += ha*w10;
    float s1b = x0b*w0 + x1b*w1 + x2b*w2;
    float s2b = m0b*w3 + m1b*w4 + m2b*w5;
    float hb = fmaxf(s1b + s2b + w6, 0.0f);
    p0b += hb*w7;  p1b += hb*w8;  q0b += hb*w9;  q1b += hb*w10;
  }
  P[2*e1] = p0a; P[2*e1+1] = p1a; Q[2*e1] = q0a; Q[2*e1+1] = q1a;
  if (v2) { P[2*e2] = p0b; P[2*e2+1] = p1b; Q[2*e2] = q0b; Q[2*e2+1] = q1b; }
}

__device__ __forceinline__ void score_one(int e, const float* P, const float* Q,
                                          const u32* segoff, const u64* kp, const u32* feid,
                                          float b20, float b21, float* yo, u32* ymo) {
  u32 st = segoff[e], en = segoff[e+1];
  float a0, a1, dummy;
  agg_neighbors(e, st, en, kp, feid, Q, 2, &a0, &a1, &dummy);
  float dg = (float)(2u*(en - st) + 1u);
  float z0 = P[2*e]   + a0/dg + b20;
  float z1 = P[2*e+1] + a1/dg + b21;
  float l0 = 1.0f/(1.0f + expf(-z0));
  float l1 = 1.0f/(1.0f + expf(-z1));
  u32 g0b, g1b;
  { u32 o0,o1; tf2x32(0u, 2u*(u32)e,      o0, o1); g0b = o0 ^ o1; }
  { u32 o0,o1; tf2x32(0u, 2u*(u32)e + 1u, o0, o1); g1b = o0 ^ o1; }
  float U0 = __uint_as_float((g0b>>9) | 0x3f800000u) - 1.0f;
  float U1 = __uint_as_float((g1b>>9) | 0x3f800000u) - 1.0f;
  float g0 = -logf(-logf(U0 + 1e-20f) + 1e-20f);
  float g1 = -logf(-logf(U1 + 1e-20f) + 1e-20f);
  float A0 = (l0 + g0)/0.1f;
  float A1 = (l1 + g1)/0.1f;
  float mx = fmaxf(A0, A1);
  float e0 = expf(A0-mx), e1v = expf(A1-mx);
  float y = e0/(e0+e1v);
  *yo = y;
  *ymo = __float_as_uint(y) | 0x80000000u;
}

__global__ void k_scores(const float* __restrict__ P, const float* __restrict__ Q,
                         const u32* __restrict__ segoff, const u64* __restrict__ kp,
                         const u32* __restrict__ feid,
                         const float* __restrict__ b2, const u32* __restrict__ scal,
                         float* __restrict__ Y, u32* __restrict__ ymap) {
  int e1 = blockIdx.x*256 + threadIdx.x;
  int E = (int)scal[S_E];
  if (e1 >= E) return;
  int e2 = e1 + HALF1;
  bool v2 = e2 < E;
  int e2c = v2 ? e2 : e1;
  float b20 = b2[0], b21 = b2[1];
  float ya, yb; u32 ma, mb;
  score_one(e1,  P, Q, segoff, kp, feid, b20, b21, &ya, &ma);
  score_one(e2c, P, Q, segoff, kp, feid, b20, b21, &yb, &mb);
  Y[e1] = ya; ymap[e1] = ma;
  if (v2) { Y[e2] = yb; ymap[e2] = mb; }
}

// ---------------- exact top-k: fused histogram + last-block select ----------------
__global__ void k_tkround(const u32* __restrict__ ymap, u32* __restrict__ scal,
                          u32* __restrict__ hist, u32* __restrict__ done, int byte) {
  __shared__ u32 h[256];
  __shared__ u32 s2[256];
  __shared__ u32 chosen_s;
  __shared__ u32 lastflag;
  int t = threadIdx.x;
  h[t] = 0u;
  if (t == 0) lastflag = 0u;
  __syncthreads();
  int E = (int)scal[S_E];
  u32 pfx = scal[S_PFX];
  int base = blockIdx.x*1024;
  for (int k = 0; k < 4; ++k) {
    int e = base + k*256 + t;
    if (e < E) {
      u32 u = ymap[e];
      bool match = (byte == 3) || ((u >> ((byte+1)*8)) == pfx);
      if (match) atomicAdd(&h[(u >> (byte*8)) & 255u], 1u);
    }
  }
  __syncthreads();
  u32 c = h[t];
  if (c) atomicAdd(&hist[t], c);
  __syncthreads();
  if (t == 0) {
    __threadfence();
    u32 old = atomicAdd(&done[byte], 1u);
    if (old == gridDim.x - 1u) lastflag = 1u;
  }
  __syncthreads();
  if (!lastflag) return;
  __threadfence();
  u32 v = atomicExch(&hist[t], 0u);
  s2[t] = v;
  if (t == 0) chosen_s = 0u;
  __syncthreads();
  for (int o = 1; o < 256; o <<= 1) {
    u32 x = (t + o < 256) ? s2[t+o] : 0u; __syncthreads();
    s2[t] += x; __syncthreads();
  }
  u32 krem = scal[S_KREM];
  if (s2[t] >= krem) atomicMax(&chosen_s, (u32)t);
  __syncthreads();
  if (t == 0) {
    u32 chosen = chosen_s;
    u32 sufnext = (chosen < 255u) ? s2[chosen+1] : 0u;
    u32 newkrem = krem - sufnext;
    u32 npfx = (scal[S_PFX] << 8) | chosen;
    scal[S_PFX] = npfx; scal[S_KREM] = newkrem;
    if (byte == 0) { scal[S_TU] = npfx; scal[S_R] = newkrem; }
  }
}

// ---------------- mesh collapse ----------------
__global__ void k_catfused(const u32* __restrict__ feid, const u32* __restrict__ sel,
                           u32* __restrict__ cat, u32* __restrict__ ch) {
  __shared__ u32 h[8];
  int t = threadIdx.x;
  if (t < 8) h[t] = 0u;
  __syncthreads();
  int base = blockIdx.x*1024 + t*4;
  for (int k = 0; k < 4; ++k) {
    int f = base + k;
    if (f < FN) {
      u32 m0 = sel[feid[f*3]], m1 = sel[feid[f*3+1]], m2 = sel[feid[f*3+2]];
      u32 pen = m0 + m1 + m2;
      u32 psi = m1 + 2u*m2;
      u32 c = (pen == 0) ? 0u : (pen == 1) ? (1u+psi) : (pen == 2) ? (3u+psi) : 7u;
      cat[f] = c;
      atomicAdd(&h[c], 1u);
    }
  }
  __syncthreads();
  if (t < 8) ch[(u32)t*NBC + blockIdx.x] = h[t];
}

__global__ void k_catoff(u32* __restrict__ ch, u32* __restrict__ scal) {
  __shared__ u32 lds[256];
  __shared__ u32 ex[1024];
  int t = threadIdx.x;
  u32 v[4]; u32 tot = 0;
  for (int k = 0; k < 4; ++k) {
    int i = t*4 + k;
    u32 x = (i < 8*NBC) ? ch[i] : 0u;
    v[k] = x; tot += x;
  }
  lds[t] = tot; __syncthreads();
  for (int o = 1; o < 256; o <<= 1) {
    u32 x = (t >= o) ? lds[t-o] : 0u; __syncthreads();
    lds[t] += x; __syncthreads();
  }
  u32 excl = lds[t] - tot;
  u32 run = excl;
  for (int k = 0; k < 4; ++k) { ex[t*4+k] = run; run += v[k]; }
  __syncthreads();
  for (int k = 0; k < 4; ++k) {
    int i = t*4 + k;
    if (i < 8*NBC) ch[i] = ex[i];
  }
  if (t == 0) {
    u32 total = lds[255];
    u32 bnd[9];
    for (int c = 0; c < 8; ++c) bnd[c] = ex[c*NBC];
    bnd[8] = total;
    u32 tot8[8];
    for (int c = 0; c < 8; ++c) tot8[c] = bnd[c+1] - bnd[c];
    u32 n0 = tot8[0], n1 = tot8[1]+tot8[2]+tot8[3], n2 = tot8[4]+tot8[5]+tot8[6], n3 = tot8[7];
    u32 NF = n0 + 2u*n1 + 3u*n2 + 4u*n3;
    u32 E = scal[S_E], num = scal[S_NUM];
    u32 NEn = (u32)VN + num + 3u*NF;
    scal[S_NF] = NF; scal[S_NEN] = NEn;
    scal[S_O1] = 2u*E;
    scal[S_O2] = 2u*E + 3u*NF;
    scal[S_O3] = 2u*E + 3u*NF + 2u*NEn;
    u32 RS[8] = {0u, n0,n0,n0, n0+2u*n1, n0+2u*n1, n0+2u*n1, n0+2u*n1+3u*n2};
    u32 GS[8] = {0u, n1,n1,n1, n2,n2,n2, n3};
    u32 GP[8] = {0u, n0,n0,n0, n0+n1, n0+n1, n0+n1, n0+n1+n2};
    for (int i = 0; i < 8; ++i) { scal[S_RS+i] = RS[i]; scal[S_GS+i] = GS[i]; scal[S_GP+i] = GP[i]; }
  }
}

__global__ void k_catrank(const u32* __restrict__ cat, const u32* __restrict__ ch,
                          u32* __restrict__ cr) {
  __shared__ u32 lds[256];
  int t = threadIdx.x;
  int base = blockIdx.x*1024 + t*4;
  u32 cc[4], loc[4];
  u32 cnt[8] = {0,0,0,0,0,0,0,0};
  for (int k = 0; k < 4; ++k) {
    int i = base + k;
    if (i < FN) { u32 c = cat[i]; cc[k] = c; loc[k] = cnt[c]++; }
    else cc[k] = 8u;
  }
  u32 tb[8];
  for (int c = 0; c < 8; ++c) {
    lds[t] = cnt[c]; __syncthreads();
    for (int o = 1; o < 256; o <<= 1) {
      u32 x = (t >= o) ? lds[t-o] : 0u; __syncthreads();
      lds[t] += x; __syncthreads();
    }
    tb[c] = lds[t] - cnt[c];
    __syncthreads();
  }
  for (int k = 0; k < 4; ++k) {
    int i = base + k;
    if (i < FN) { u32 c = cc[k]; cr[i] = ch[c*NBC + blockIdx.x] + tb[c] + loc[k]; }
  }
}

__global__ void k_wfaces(const int* __restrict__ face, const u32* __restrict__ cat,
                         const u32* __restrict__ cr, const u32* __restrict__ feid,
                         const u32* __restrict__ selr, const u32* __restrict__ scal,
                         int* __restrict__ nfi, float* __restrict__ dout) {
  int f = blockIdx.x*256 + threadIdx.x;
  if (f >= FN) return;
  const int nfc[8] = {1,2,2,2,3,3,3,4};
  const int tri[8][4][3] = {
    {{0,2,4},{0,0,0},{0,0,0},{0,0,0}},
    {{0,1,4},{1,2,4},{0,0,0},{0,0,0}},
    {{2,3,0},{3,4,0},{0,0,0},{0,0,0}},
    {{4,5,2},{5,0,2},{0,0,0},{0,0,0}},
    {{0,1,4},{1,2,3},{1,3,4},{0,0,0}},
    {{4,5,2},{5,0,1},{5,1,2},{0,0,0}},
    {{2,3,0},{3,4,5},{3,5,0},{0,0,0}},
    {{0,1,5},{1,2,3},{1,3,5},{3,4,5}}};
  u32 c = cat[f];
  int cv[6];
  cv[0] = face[f*3];   cv[2] = face[f*3+1]; cv[4] = face[f*3+2];
  cv[1] = VN + (int)selr[feid[f*3]];
  cv[3] = VN + (int)selr[feid[f*3+1]];
  cv[5] = VN + (int)selr[feid[f*3+2]];
  u32 g  = cr[f] - scal[S_GP + c];
  u32 o1 = scal[S_O1];
  for (int j = 0; j < nfc[c]; ++j) {
    u32 row = scal[S_RS + c] + (u32)j*scal[S_GS + c] + g;
    for (int m = 0; m < 3; ++m) {
      int v = cv[tri[c][j][m]];
      nfi[row*3 + m] = v;
      dout[o1 + row*3 + m] = (float)v;
    }
  }
}

__global__ void k_wne(const int* __restrict__ nfi, const u32* __restrict__ scal,
                      float* __restrict__ dout) {
  int i = blockIdx.x*256 + threadIdx.x;
  u32 NEn = scal[S_NEN];
  if (i >= (int)NEn) return;
  u32 NF = scal[S_NF];
  u32 Vp = (u32)VN + scal[S_NUM];
  u32 o2 = scal[S_O2];
  int a, b;
  if ((u32)i < Vp) { a = i; b = i; }
  else {
    u32 j = (u32)i - Vp;
    u32 blk = j / NF, r = j - blk*NF;
    int i0 = (blk == 0) ? 0 : (blk == 1) ? 1 : 2;
    int i1 = (blk == 0) ? 1 : (blk == 1) ? 2 : 0;
    a = nfi[r*3 + i0]; b = nfi[r*3 + i1];
  }
  dout[o2 + i] = (float)a;
  dout[o2 + NEn + i] = (float)b;
}

__global__ void k_wmask(const u32* __restrict__ sel, const float* __restrict__ Y,
                        const u32* __restrict__ scal, float* __restrict__ dout) {
  int e = blockIdx.x*256 + threadIdx.x;
  if (e >= (int)scal[S_E]) return;
  float y = Y[e];
  float yh = sel[e] ? 1.0f : 0.0f;
  dout[scal[S_O3] + e] = (yh - y) + y;
}

// ---------------- host-side drivers ----------------
static void radix_pass(u32* hist, u32* histnext, u32* sums, u64* kin, u64* kout,
                       int shift, hipStream_t st) {
  scan_blocks<<<NBS, 256, 0, st>>>(hist, hist, sums, NB1*256, histnext);
  scan_sums<<<1, 256, 0, st>>>(sums, NBS);
  k_rscat<<<NB1, 256, 0, st>>>(kin, kout, hist, sums, shift, NB1, histnext);
}

extern "C" void kernel_launch(void* const* d_in, const int* in_sizes, int n_in,
                              void* d_out, int out_size, void* d_ws, size_t ws_size,
                              hipStream_t stream) {
  const float* x    = (const float*)d_in[0];
  const int*   face = (const int*)d_in[1];
  const int*   divp = (const int*)d_in[4];
  const float* W1s  = (const float*)d_in[5];
  const float* W1n  = (const float*)d_in[6];
  const float* b1   = (const float*)d_in[7];
  const float* W2s  = (const float*)d_in[8];
  const float* W2n  = (const float*)d_in[9];
  const float* b2   = (const float*)d_in[10];
  float* out = (float*)d_out;
  u32* W = (u32*)d_ws;

  u64 *KPA = (u64*)(W+W_KPA), *KPB = (u64*)(W+W_KPB);
  u32 *HIST = W+W_HIST, *HIST2 = W+W_HIST2, *SUMS = W+W_SUMS, *SCAL = W+W_SCAL;
  u32 *TKH = W+W_TKH, *DONE = W+W_DONE;
  u32 *RK = W+W_T64;                  // rank partials (T64 region unused until scan64)
  u64 *T64 = (u64*)(W+W_T64);
  u64 *SUMS64 = (u64*)(W+W_SUMS);

  // 1) keys (+pass0 hist +weight pack +inits); 4 radix passes, no separate hist kernels
  k_keys<<<NB1, 256, 0, stream>>>(face, W1s, W1n, b1, W2s, W2n, (float*)(W+W_PK),
                                  KPA, HIST, TKH, DONE);
  radix_pass(HIST,  HIST2,   SUMS, KPA, KPB,  0, stream);
  radix_pass(HIST2, HIST,    SUMS, KPB, KPA,  8, stream);
  radix_pass(HIST,  HIST2,   SUMS, KPA, KPB, 16, stream);
  radix_pass(HIST2, nullptr, SUMS, KPB, KPA, 24, stream);
  scan_flagblocks<<<NBS, 256, 0, stream>>>(KPA, RK, SUMS, K3F);
  scan_sums<<<1, 256, 0, stream>>>(SUMS, NBS);
  k_uwrite<<<NB1, 256, 0, stream>>>(KPA, RK, SUMS, x, W+W_SEGOFF, W+W_FEID,
                                    (float*)(W+W_XE), out, SCAL, divp);

  // 2) GSN conv layers (2 edges/thread for ILP)
  k_l12<<<NBL, 256, 0, stream>>>((float*)(W+W_XE), W+W_SEGOFF, KPA, W+W_FEID, SCAL,
                                 (float*)(W+W_PK), (float*)(W+W_P), (float*)(W+W_Q));
  k_scores<<<NBL, 256, 0, stream>>>((float*)(W+W_P), (float*)(W+W_Q), W+W_SEGOFF, KPA,
                                    W+W_FEID, b2, SCAL, (float*)(W+W_Y), W+W_YMAP);

  // 3) exact top-k (fused hist+select per byte) + packed u64 scan for sel/selr
  for (int byte = 3; byte >= 0; --byte)
    k_tkround<<<NBH, 256, 0, stream>>>(W+W_YMAP, SCAL, TKH, DONE, byte);
  scan64_src<<<NBS, 256, 0, stream>>>(W+W_YMAP, SCAL, T64, SUMS64);
  scan64_sums<<<1, 256, 0, stream>>>(SUMS64, NBS);
  k_sel2<<<NB1, 256, 0, stream>>>(W+W_YMAP, T64, SUMS64, SCAL, W+W_SEL, W+W_SELR);

  // 4) mesh collapse
  k_catfused<<<NBC, 256, 0, stream>>>(W+W_FEID, W+W_SEL, W+W_CAT, W+W_CATH);
  k_catoff<<<1, 256, 0, stream>>>(W+W_CATH, SCAL);
  k_catrank<<<NBC, 256, 0, stream>>>(W+W_CAT, W+W_CATH, W+W_CATR);
  k_wfaces<<<391, 256, 0, stream>>>(face, W+W_CAT, W+W_CATR, W+W_FEID, W+W_SELR, SCAL,
                                    (int*)(W+W_NFI), out);
  k_wne<<<5118, 256, 0, stream>>>((int*)(W+W_NFI), SCAL, out);
  k_wmask<<<NB1, 256, 0, stream>>>(W+W_SEL, (float*)(W+W_Y), SCAL, out);
}

// Round 9
// 316.292 us; speedup vs baseline: 4.3709x; 1.0868x over previous
//
#include <hip/hip_runtime.h>
#include <stdint.h>

typedef uint32_t u32;
typedef uint64_t u64;

#define VN 50000
#define FN 100000
#define K3F 300000
#define EMAX 300000
#define NB1 1172          // ceil(300000/256); NB1*256 = 300032
#define NBS 293           // 293*1024 = 300032
#define NBH 293
#define NBC 98            // ceil(100000/1024)
#define HALF1 150016      // 586*256
#define NBL 586

// ---------------- workspace layout (u32 units) ----------------
#define W_KPA    0u        // 600000 (300000 u64) ping
#define W_KPB    600000u   // 600000 pong
#define W_SEGOFF 1200000u  // 300001
#define W_FEID   1500004u  // 300000
#define W_XE     1800004u  // 900000 f32
#define W_PK     2700004u  // 3072 f32 packed weights
#define W_P      2703076u  // 600000 f32
#define W_Q      3303076u  // 600000 f32
#define W_Y      3903076u  // 300000 f32
#define W_YMAP   4203076u  // 300000
#define W_T64    4503076u  // 600064 (u64 region; even offset; also rank tmp before scan64)
#define W_SEL    5103140u  // 300000
#define W_SELR   5403140u  // 300000
#define W_CAT    5703140u  // 100000
#define W_CATR   5803140u  // 100000
#define W_NFI    5903140u  // 1200000 int
#define W_HIST   7103140u  // 300032
#define W_HIST2  7403172u  // 300032
#define W_SUMS   7703204u  // 4096 (even -> u64-reusable)
#define W_CATH   7707300u  // 1024
#define W_TKH    7708324u  // 256
#define W_DONE   7708580u  // 32
#define W_SCAL   7708612u  // 64

#define S_E 0
#define S_NUM 1
#define S_PFX 2
#define S_KREM 3
#define S_TU 4
#define S_R 5
#define S_NF 6
#define S_NEN 7
#define S_O1 8
#define S_O2 9
#define S_O3 10
#define S_RS 16
#define S_GS 24
#define S_GP 32

// ---------------- threefry2x32, key = (0, 42) ----------------
__device__ __forceinline__ void tf2x32(u32 x0, u32 x1, u32& o0, u32& o1) {
  const u32 ks0 = 0u, ks1 = 42u, ks2 = 0x1BD11BDAu ^ 0u ^ 42u;
  x0 += ks0; x1 += ks1;
#define TFR(r) { x0 += x1; x1 = (x1<<(r))|(x1>>(32-(r))); x1 ^= x0; }
  TFR(13) TFR(15) TFR(26) TFR(6)   x0 += ks1; x1 += ks2 + 1u;
  TFR(17) TFR(29) TFR(16) TFR(24)  x0 += ks2; x1 += ks0 + 2u;
  TFR(13) TFR(15) TFR(26) TFR(6)   x0 += ks0; x1 += ks1 + 3u;
  TFR(17) TFR(29) TFR(16) TFR(24)  x0 += ks1; x1 += ks2 + 4u;
  TFR(13) TFR(15) TFR(26) TFR(6)   x0 += ks2; x1 += ks0 + 5u;
#undef TFR
  o0 = x0; o1 = x1;
}

// ---------------- scans: block-partial prefix + RAW block sums ----------------
// (no scan_sums dispatch — consumers prefix the 293 raw sums redundantly)
__global__ void scan_blocks(const u32* __restrict__ in, u32* __restrict__ out,
                            u32* __restrict__ sums, int n) {
  __shared__ u32 lds[256];
  int t = threadIdx.x;
  int base = blockIdx.x*1024 + t*4;
  u32 v[4]; u32 tot = 0;
  for (int k = 0; k < 4; ++k) { v[k] = (base+k < n) ? in[base+k] : 0u; tot += v[k]; }
  lds[t] = tot; __syncthreads();
  for (int o = 1; o < 256; o <<= 1) {
    u32 x = (t >= o) ? lds[t-o] : 0u; __syncthreads();
    lds[t] += x; __syncthreads();
  }
  u32 excl = lds[t] - tot;
  if (t == 255) sums[blockIdx.x] = lds[255];
  u32 run = excl;
  for (int k = 0; k < 4; ++k) { if (base+k < n) out[base+k] = run; run += v[k]; }
}

__global__ void scan_flagblocks(const u64* __restrict__ kp, u32* __restrict__ out,
                                u32* __restrict__ sums, int n) {
  __shared__ u32 lds[256];
  int t = threadIdx.x;
  int base = blockIdx.x*1024 + t*4;
  u32 v[4]; u32 tot = 0;
  for (int k = 0; k < 4; ++k) {
    int i = base + k;
    u32 f = 0;
    if (i < n) f = (i == 0 || (u32)(kp[i-1]>>32) != (u32)(kp[i]>>32)) ? 1u : 0u;
    v[k] = f; tot += f;
  }
  lds[t] = tot; __syncthreads();
  for (int o = 1; o < 256; o <<= 1) {
    u32 x = (t >= o) ? lds[t-o] : 0u; __syncthreads();
    lds[t] += x; __syncthreads();
  }
  u32 excl = lds[t] - tot;
  if (t == 255) sums[blockIdx.x] = lds[255];
  u32 run = excl;
  for (int k = 0; k < 4; ++k) { if (base+k < n) out[base+k] = run; run += v[k]; }
}

// ---------------- u64 packed per-block scan (gt lo32, tie hi32), RAW sums ----------------
__global__ void scan64_src(const u32* __restrict__ ymap, const u32* __restrict__ scal,
                           u64* __restrict__ part, u64* __restrict__ sums) {
  __shared__ u64 lds[256];
  int t = threadIdx.x;
  int base = blockIdx.x*1024 + t*4;
  int E = (int)scal[S_E];
  u32 TU = scal[S_TU];
  u64 v[4]; u64 tot = 0;
  for (int k = 0; k < 4; ++k) {
    int e = base + k;
    u64 val = 0;
    if (e < E) {
      u32 u = ymap[e];
      if (u > TU) val = 1ull;
      else if (u == TU) val = 1ull << 32;
    }
    v[k] = val; tot += val;
  }
  lds[t] = tot; __syncthreads();
  for (int o = 1; o < 256; o <<= 1) {
    u64 x = (t >= o) ? lds[t-o] : 0ull; __syncthreads();
    lds[t] += x; __syncthreads();
  }
  u64 excl = lds[t] - tot;
  if (t == 255) sums[blockIdx.x] = lds[255];
  u64 run = excl;
  for (int k = 0; k < 4; ++k) { part[base+k] = run; run += v[k]; }
}

// sel + selr; each block (1024 elems, chunk == blockIdx) sums sums[0..b-1] redundantly
__global__ void k_sel2(const u32* __restrict__ ymap, const u64* __restrict__ part,
                       const u64* __restrict__ sums, const u32* __restrict__ scal,
                       u32* __restrict__ sel, u32* __restrict__ selr) {
  __shared__ u64 sl64[256];
  int t = threadIdx.x, b = blockIdx.x;
  u64 partial = 0;
  for (int j = t; j < b; j += 256) partial += sums[j];
  sl64[t] = partial; __syncthreads();
  for (int o = 128; o; o >>= 1) { if (t < o) sl64[t] += sl64[t+o]; __syncthreads(); }
  u64 basepre = sl64[0];
  int E = (int)scal[S_E];
  u32 TU = scal[S_TU], R = scal[S_R];
  for (int k = 0; k < 4; ++k) {
    int e = b*1024 + k*256 + t;
    if (e >= EMAX) continue;
    u64 pre = part[e] + basepre;
    u32 GTpre = (u32)pre, TIEpre = (u32)(pre >> 32);
    u32 v = 0;
    if (e < E) {
      u32 u = ymap[e];
      v = (u > TU) || (u == TU && TIEpre < R);
    }
    sel[e] = v ? 1u : 0u;
    selr[e] = GTpre + min(TIEpre, R);
  }
}

// ---------------- radix sort over packed u64 (key in hi32), 8-bit LSD ----------------
__global__ void k_rhist(const u64* __restrict__ kp, u32* __restrict__ hist,
                        int shift, int nb) {
  __shared__ u32 h[256];
  int t = threadIdx.x;
  h[t] = 0; __syncthreads();
  int i = blockIdx.x*256 + t;
  if (i < K3F) atomicAdd(&h[((u32)(kp[i]>>32) >> shift) & 255u], 1u);
  __syncthreads();
  hist[(u32)t*nb + blockIdx.x] = h[t];
}

// scatter; sums holds RAW 293 block totals — full prefix built in LDS (two-half scan)
__global__ void k_rscat(const u64* __restrict__ kp, u64* __restrict__ okp,
                        const u32* __restrict__ hist, const u32* __restrict__ sums,
                        int shift, int nb) {
  __shared__ u32 sl[256];
  __shared__ u32 ps[NBS];
  __shared__ u64 ball[4][8];
  __shared__ u64 vmask[4];
  int t = threadIdx.x, w = t>>6, lane = t&63;
  // build exclusive prefix of the 293 raw sums
  u32 a0 = (t < NBS) ? sums[t] : 0u;
  u32 a1 = (256 + t < NBS) ? sums[256+t] : 0u;
  sl[t] = a0; __syncthreads();
  for (int o = 1; o < 256; o <<= 1) {
    u32 x = (t >= o) ? sl[t-o] : 0u; __syncthreads();
    sl[t] += x; __syncthreads();
  }
  u32 incl0 = sl[t], tot0 = sl[255];
  if (t < NBS) ps[t] = incl0 - a0;
  __syncthreads();
  sl[t] = a1; __syncthreads();
  for (int o = 1; o < 256; o <<= 1) {
    u32 x = (t >= o) ? sl[t-o] : 0u; __syncthreads();
    sl[t] += x; __syncthreads();
  }
  if (256 + t < NBS) ps[256+t] = sl[t] - a1 + tot0;
  __syncthreads();
  int i = blockIdx.x*256 + t;
  bool valid = i < K3F;
  u64 v = valid ? kp[i] : 0ull;
  u32 d = ((u32)(v>>32) >> shift) & 255u;
  for (int bit = 0; bit < 8; ++bit) {
    u64 bm = __ballot(valid && ((d>>bit)&1u));
    if (lane == 0) ball[w][bit] = bm;
  }
  u64 vb = __ballot(valid ? 1 : 0);
  if (lane == 0) vmask[w] = vb;
  __syncthreads();
  if (valid) {
    u32 rank = 0;
    for (int ww = 0; ww < w; ++ww) {
      u64 m = vmask[ww];
      for (int bit = 0; bit < 8; ++bit) { u64 bb = ball[ww][bit]; m &= ((d>>bit)&1u) ? bb : ~bb; }
      rank += (u32)__popcll(m);
    }
    u64 m = vmask[w];
    for (int bit = 0; bit < 8; ++bit) { u64 bb = ball[w][bit]; m &= ((d>>bit)&1u) ? bb : ~bb; }
    rank += (u32)__popcll(m & ((1ull<<lane)-1ull));
    u32 h = d*(u32)nb + blockIdx.x;
    u32 pos = hist[h] + ps[h>>10] + rank;
    okp[pos] = v;       // single clean 8B scatter, no extra atomics
  }
}

// ---------------- pipeline kernels ----------------
__global__ void k_keys(const int* __restrict__ face,
                       const float* __restrict__ W1s, const float* __restrict__ W1n,
                       const float* __restrict__ b1,
                       const float* __restrict__ W2s, const float* __restrict__ W2n,
                       float* __restrict__ pk,
                       u64* __restrict__ kp, u32* __restrict__ hist,
                       u32* __restrict__ tkh, u32* __restrict__ done) {
  __shared__ u32 h[256];
  int t = threadIdx.x;
  h[t] = 0;
  __syncthreads();
  if (blockIdx.x == 0) {
    tkh[t] = 0u;
    if (t < 32) done[t] = 0u;
    float* p = pk + t*12;
    p[0] = W1s[t]; p[1] = W1s[256+t]; p[2] = W1s[512+t];
    p[3] = W1n[t]; p[4] = W1n[256+t]; p[5] = W1n[512+t];
    p[6] = b1[t];
    p[7] = W2s[2*t]; p[8] = W2s[2*t+1];
    p[9] = W2n[2*t]; p[10] = W2n[2*t+1];
    p[11] = 0.0f;
  }
  int i = blockIdx.x*256 + t;
  if (i < K3F) {
    int s = i / FN, f = i - s*FN;
    int v0 = face[f*3 + s];
    int v1 = face[f*3 + (s == 2 ? 0 : s+1)];
    int a = min(v0, v1), b = max(v0, v1);
    u32 key = ((u32)a * (u32)VN + (u32)b) ^ 0x80000000u;  // biased int32-wrap key
    kp[i] = ((u64)key << 32) | (u32)i;                     // payload = orig index
    atomicAdd(&h[key & 255u], 1u);
  }
  __syncthreads();
  hist[(u32)t*NB1 + blockIdx.x] = h[t];
}

// unique + segoff + feid + edge-node outputs + xe + tk init; sums = RAW flag totals
__global__ void k_uwrite(const u64* __restrict__ kp, const u32* __restrict__ rankp,
                         const u32* __restrict__ sums, const float* __restrict__ x,
                         u32* __restrict__ segoff, u32* __restrict__ feid,
                         float* __restrict__ xe, float* __restrict__ dout,
                         u32* __restrict__ scal, const int* __restrict__ divp) {
  __shared__ u32 sl[256];
  int t = threadIdx.x, b = blockIdx.x;
  int chunk = b >> 2;             // all 256 elems of this block share p>>10 == chunk
  u32 partial = 0;
  for (int j = t; j < chunk; j += 256) partial += sums[j];
  sl[t] = partial; __syncthreads();
  for (int o = 128; o; o >>= 1) { if (t < o) sl[t] += sl[t+o]; __syncthreads(); }
  u32 basepre = sl[0];
  int p = b*256 + t;
  if (p >= K3F) return;
  u64 v = kp[p];
  u32 cur = (u32)(v >> 32);
  u32 fl = (p == 0 || (u32)(kp[p-1] >> 32) != cur) ? 1u : 0u;
  u32 rk = rankp[p] + basepre;
  if (fl) {
    u32 e = rk;
    segoff[e] = (u32)p;
    int k = (int)(cur ^ 0x80000000u);
    long long kk = (long long)k;
    long long qq = (kk - (kk < 0 ? (long long)(VN-1) : 0ll)) / VN; // floor div
    int q = (int)qq;
    int r = (int)(kk - qq * VN);
    dout[2*e]   = (float)q;
    dout[2*e+1] = (float)r;
    u32 i0 = (u32)(q < 0 ? q + VN : q);  // numpy negative-index wrap
    u32 i1 = (u32)r;
    for (int c = 0; c < 3; ++c) xe[e*3+c] = 0.5f*(x[i0*3+c] + x[i1*3+c]);
  }
  u32 id = rk - 1u + fl;
  u32 i = (u32)v;
  u32 s = i / FN, f = i - s*FN;
  feid[f*3 + s] = id;
  if (p == K3F-1) {
    u32 E = rk + fl;
    u32 num = E / (u32)divp[0];
    scal[S_E] = E; scal[S_NUM] = num;
    segoff[E] = (u32)K3F;
    scal[S_PFX] = 0u; scal[S_KREM] = num;   // top-k init (fused)
  }
}

// Neighbor aggregation direct from key-sort segments (bit-exact reference order).
__device__ __forceinline__ void agg_neighbors(int e, u32 st, u32 en,
                                              const u64* __restrict__ kp,
                                              const u32* __restrict__ feid,
                                              const float* __restrict__ v, int stride,
                                              float* acc0, float* acc1, float* acc2) {
  const int sslot[6] = {0,1,1,2,2,0};
  const int dslot[6] = {1,0,2,1,0,2};
  float c0 = 0.f, c1 = 0.f, c2 = 0.f;
  for (int b = 0; b < 6; ++b) {
    int j = dslot[b], isl = sslot[b];
    for (u32 p = st; p < en; ++p) {
      u32 i = (u32)kp[p];
      u32 s = i / FN;
      if ((int)s == j) {
        u32 f = i - s*FN;
        u32 u = feid[f*3 + isl];
        c0 += v[u*stride]; c1 += v[u*stride+1]; if (stride == 3) c2 += v[u*stride+2];
      }
    }
  }
  c0 += v[e*stride]; c1 += v[e*stride+1]; if (stride == 3) c2 += v[e*stride+2];
  *acc0 = c0; *acc1 = c1; *acc2 = c2;
}

// fused neighbor-mean + layer1 + projection, 2 edges/thread (ILP), scalar weights
__global__ void k_l12(const float* __restrict__ xe, const u32* __restrict__ segoff,
                      const u64* __restrict__ kp, const u32* __restrict__ feid,
                      const u32* __restrict__ scal, const float* __restrict__ pk,
                      float* __restrict__ P, float* __restrict__ Q) {
  int e1 = blockIdx.x*256 + threadIdx.x;
  int E = (int)scal[S_E];
  if (e1 >= E) return;
  int e2 = e1 + HALF1;
  bool v2 = e2 < E;
  int e2c = v2 ? e2 : e1;
  u32 st1 = segoff[e1], en1 = segoff[e1+1];
  u32 st2 = segoff[e2c], en2 = segoff[e2c+1];
  float c0a,c1a,c2a, c0b,c1b,c2b;
  agg_neighbors(e1,  st1, en1, kp, feid, xe, 3, &c0a,&c1a,&c2a);
  agg_neighbors(e2c, st2, en2, kp, feid, xe, 3, &c0b,&c1b,&c2b);
  float x0a=xe[e1*3],  x1a=xe[e1*3+1],  x2a=xe[e1*3+2];
  float x0b=xe[e2c*3], x1b=xe[e2c*3+1], x2b=xe[e2c*3+2];
  float dga = (float)(2u*(en1-st1)+1u), dgb = (float)(2u*(en2-st2)+1u);
  float m0a=c0a/dga, m1a=c1a/dga, m2a=c2a/dga;
  float m0b=c0b/dgb, m1b=c1b/dgb, m2b=c2b/dgb;
  float p0a=0,p1a=0,q0a=0,q1a=0, p0b=0,p1b=0,q0b=0,q1b=0;
#pragma unroll 4
  for (int hh = 0; hh < 256; ++hh) {
    const float* w = pk + hh*12;
    float w0=w[0],w1=w[1],w2=w[2],w3=w[3],w4=w[4],w5=w[5],w6=w[6];
    float w7=w[7],w8=w[8],w9=w[9],w10=w[10];
    float s1a = x0a*w0 + x1a*w1 + x2a*w2;
    float s2a = m0a*w3 + m1a*w4 + m2a*w5;
    float ha = fmaxf(s1a + s2a + w6, 0.0f);
    p0a += ha*w7;  p1a += ha*w8;  q0a += ha*w9;  q1a += ha*w10;
    float s1b = x0b*w0 + x1b*w1 + x2b*w2;
    float s2b = m0b*w3 + m1b*w4 + m2b*w5;
    float hb = fmaxf(s1b + s2b + w6, 0.0f);
    p0b += hb*w7;  p1b += hb*w8;  q0b += hb*w9;  q1b += hb*w10;
  }
  P[2*e1] = p0a; P[2*e1+1] = p1a; Q[2*e1] = q0a; Q[2*e1+1] = q1a;
  if (v2) { P[2*e2] = p0b; P[2*e2+1] = p1b; Q[2*e2] = q0b; Q[2*e2+1] = q1b; }
}

__device__ __forceinline__ void score_one(int e, const float* P, const float* Q,
                                          const u32* segoff, const u64* kp, const u32* feid,
                                          float b20, float b21, float* yo, u32* ymo) {
  u32 st = segoff[e], en = segoff[e+1];
  float a0, a1, dummy;
  agg_neighbors(e, st, en, kp, feid, Q, 2, &a0, &a1, &dummy);
  float dg = (float)(2u*(en - st) + 1u);
  float z0 = P[2*e]   + a0/dg + b20;
  float z1 = P[2*e+1] + a1/dg + b21;
  float l0 = 1.0f/(1.0f + expf(-z0));
  float l1 = 1.0f/(1.0f + expf(-z1));
  u32 g0b, g1b;
  { u32 o0,o1; tf2x32(0u, 2u*(u32)e,      o0, o1); g0b = o0 ^ o1; }
  { u32 o0,o1; tf2x32(0u, 2u*(u32)e + 1u, o0, o1); g1b = o0 ^ o1; }
  float U0 = __uint_as_float((g0b>>9) | 0x3f800000u) - 1.0f;
  float U1 = __uint_as_float((g1b>>9) | 0x3f800000u) - 1.0f;
  float g0 = -logf(-logf(U0 + 1e-20f) + 1e-20f);
  float g1 = -logf(-logf(U1 + 1e-20f) + 1e-20f);
  float A0 = (l0 + g0)/0.1f;
  float A1 = (l1 + g1)/0.1f;
  float mx = fmaxf(A0, A1);
  float e0 = expf(A0-mx), e1v = expf(A1-mx);
  float y = e0/(e0+e1v);
  *yo = y;
  *ymo = __float_as_uint(y) | 0x80000000u;
}

__global__ void k_scores(const float* __restrict__ P, const float* __restrict__ Q,
                         const u32* __restrict__ segoff, const u64* __restrict__ kp,
                         const u32* __restrict__ feid,
                         const float* __restrict__ b2, const u32* __restrict__ scal,
                         float* __restrict__ Y, u32* __restrict__ ymap) {
  int e1 = blockIdx.x*256 + threadIdx.x;
  int E = (int)scal[S_E];
  if (e1 >= E) return;
  int e2 = e1 + HALF1;
  bool v2 = e2 < E;
  int e2c = v2 ? e2 : e1;
  float b20 = b2[0], b21 = b2[1];
  float ya, yb; u32 ma, mb;
  score_one(e1,  P, Q, segoff, kp, feid, b20, b21, &ya, &ma);
  score_one(e2c, P, Q, segoff, kp, feid, b20, b21, &yb, &mb);
  Y[e1] = ya; ymap[e1] = ma;
  if (v2) { Y[e2] = yb; ymap[e2] = mb; }
}

// ---------------- exact top-k: fused histogram + last-block select ----------------
__global__ void k_tkround(const u32* __restrict__ ymap, u32* __restrict__ scal,
                          u32* __restrict__ hist, u32* __restrict__ done, int byte) {
  __shared__ u32 h[256];
  __shared__ u32 s2[256];
  __shared__ u32 chosen_s;
  __shared__ u32 lastflag;
  int t = threadIdx.x;
  h[t] = 0u;
  if (t == 0) lastflag = 0u;
  __syncthreads();
  int E = (int)scal[S_E];
  u32 pfx = scal[S_PFX];
  int base = blockIdx.x*1024;
  for (int k = 0; k < 4; ++k) {
    int e = base + k*256 + t;
    if (e < E) {
      u32 u = ymap[e];
      bool match = (byte == 3) || ((u >> ((byte+1)*8)) == pfx);
      if (match) atomicAdd(&h[(u >> (byte*8)) & 255u], 1u);
    }
  }
  __syncthreads();
  u32 c = h[t];
  if (c) atomicAdd(&hist[t], c);
  __syncthreads();
  if (t == 0) {
    __threadfence();
    u32 old = atomicAdd(&done[byte], 1u);
    if (old == gridDim.x - 1u) lastflag = 1u;
  }
  __syncthreads();
  if (!lastflag) return;
  __threadfence();
  u32 v = atomicExch(&hist[t], 0u);
  s2[t] = v;
  if (t == 0) chosen_s = 0u;
  __syncthreads();
  for (int o = 1; o < 256; o <<= 1) {
    u32 x = (t + o < 256) ? s2[t+o] : 0u; __syncthreads();
    s2[t] += x; __syncthreads();
  }
  u32 krem = scal[S_KREM];
  if (s2[t] >= krem) atomicMax(&chosen_s, (u32)t);
  __syncthreads();
  if (t == 0) {
    u32 chosen = chosen_s;
    u32 sufnext = (chosen < 255u) ? s2[chosen+1] : 0u;
    u32 newkrem = krem - sufnext;
    u32 npfx = (scal[S_PFX] << 8) | chosen;
    scal[S_PFX] = npfx; scal[S_KREM] = newkrem;
    if (byte == 0) { scal[S_TU] = npfx; scal[S_R] = newkrem; }
  }
}

// ---------------- mesh collapse ----------------
__global__ void k_catfused(const u32* __restrict__ feid, const u32* __restrict__ sel,
                           u32* __restrict__ cat, u32* __restrict__ ch) {
  __shared__ u32 h[8];
  int t = threadIdx.x;
  if (t < 8) h[t] = 0u;
  __syncthreads();
  int base = blockIdx.x*1024 + t*4;
  for (int k = 0; k < 4; ++k) {
    int f = base + k;
    if (f < FN) {
      u32 m0 = sel[feid[f*3]], m1 = sel[feid[f*3+1]], m2 = sel[feid[f*3+2]];
      u32 pen = m0 + m1 + m2;
      u32 psi = m1 + 2u*m2;
      u32 c = (pen == 0) ? 0u : (pen == 1) ? (1u+psi) : (pen == 2) ? (3u+psi) : 7u;
      cat[f] = c;
      atomicAdd(&h[c], 1u);
    }
  }
  __syncthreads();
  if (t < 8) ch[(u32)t*NBC + blockIdx.x] = h[t];
}

__global__ void k_catoff(u32* __restrict__ ch, u32* __restrict__ scal) {
  __shared__ u32 lds[256];
  __shared__ u32 ex[1024];
  int t = threadIdx.x;
  u32 v[4]; u32 tot = 0;
  for (int k = 0; k < 4; ++k) {
    int i = t*4 + k;
    u32 x = (i < 8*NBC) ? ch[i] : 0u;
    v[k] = x; tot += x;
  }
  lds[t] = tot; __syncthreads();
  for (int o = 1; o < 256; o <<= 1) {
    u32 x = (t >= o) ? lds[t-o] : 0u; __syncthreads();
    lds[t] += x; __syncthreads();
  }
  u32 excl = lds[t] - tot;
  u32 run = excl;
  for (int k = 0; k < 4; ++k) { ex[t*4+k] = run; run += v[k]; }
  __syncthreads();
  for (int k = 0; k < 4; ++k) {
    int i = t*4 + k;
    if (i < 8*NBC) ch[i] = ex[i];
  }
  if (t == 0) {
    u32 total = lds[255];
    u32 bnd[9];
    for (int c = 0; c < 8; ++c) bnd[c] = ex[c*NBC];
    bnd[8] = total;
    u32 tot8[8];
    for (int c = 0; c < 8; ++c) tot8[c] = bnd[c+1] - bnd[c];
    u32 n0 = tot8[0], n1 = tot8[1]+tot8[2]+tot8[3], n2 = tot8[4]+tot8[5]+tot8[6], n3 = tot8[7];
    u32 NF = n0 + 2u*n1 + 3u*n2 + 4u*n3;
    u32 E = scal[S_E], num = scal[S_NUM];
    u32 NEn = (u32)VN + num + 3u*NF;
    scal[S_NF] = NF; scal[S_NEN] = NEn;
    scal[S_O1] = 2u*E;
    scal[S_O2] = 2u*E + 3u*NF;
    scal[S_O3] = 2u*E + 3u*NF + 2u*NEn;
    u32 RS[8] = {0u, n0,n0,n0, n0+2u*n1, n0+2u*n1, n0+2u*n1, n0+2u*n1+3u*n2};
    u32 GS[8] = {0u, n1,n1,n1, n2,n2,n2, n3};
    u32 GP[8] = {0u, n0,n0,n0, n0+n1, n0+n1, n0+n1, n0+n1+n2};
    for (int i = 0; i < 8; ++i) { scal[S_RS+i] = RS[i]; scal[S_GS+i] = GS[i]; scal[S_GP+i] = GP[i]; }
  }
}

__global__ void k_catrank(const u32* __restrict__ cat, const u32* __restrict__ ch,
                          u32* __restrict__ cr) {
  __shared__ u32 lds[256];
  int t = threadIdx.x;
  int base = blockIdx.x*1024 + t*4;
  u32 cc[4], loc[4];
  u32 cnt[8] = {0,0,0,0,0,0,0,0};
  for (int k = 0; k < 4; ++k) {
    int i = base + k;
    if (i < FN) { u32 c = cat[i]; cc[k] = c; loc[k] = cnt[c]++; }
    else cc[k] = 8u;
  }
  u32 tb[8];
  for (int c = 0; c < 8; ++c) {
    lds[t] = cnt[c]; __syncthreads();
    for (int o = 1; o < 256; o <<= 1) {
      u32 x = (t >= o) ? lds[t-o] : 0u; __syncthreads();
      lds[t] += x; __syncthreads();
    }
    tb[c] = lds[t] - cnt[c];
    __syncthreads();
  }
  for (int k = 0; k < 4; ++k) {
    int i = base + k;
    if (i < FN) { u32 c = cc[k]; cr[i] = ch[c*NBC + blockIdx.x] + tb[c] + loc[k]; }
  }
}

__global__ void k_wfaces(const int* __restrict__ face, const u32* __restrict__ cat,
                         const u32* __restrict__ cr, const u32* __restrict__ feid,
                         const u32* __restrict__ selr, const u32* __restrict__ scal,
                         int* __restrict__ nfi, float* __restrict__ dout) {
  int f = blockIdx.x*256 + threadIdx.x;
  if (f >= FN) return;
  const int nfc[8] = {1,2,2,2,3,3,3,4};
  const int tri[8][4][3] = {
    {{0,2,4},{0,0,0},{0,0,0},{0,0,0}},
    {{0,1,4},{1,2,4},{0,0,0},{0,0,0}},
    {{2,3,0},{3,4,0},{0,0,0},{0,0,0}},
    {{4,5,2},{5,0,2},{0,0,0},{0,0,0}},
    {{0,1,4},{1,2,3},{1,3,4},{0,0,0}},
    {{4,5,2},{5,0,1},{5,1,2},{0,0,0}},
    {{2,3,0},{3,4,5},{3,5,0},{0,0,0}},
    {{0,1,5},{1,2,3},{1,3,5},{3,4,5}}};
  u32 c = cat[f];
  int cv[6];
  cv[0] = face[f*3];   cv[2] = face[f*3+1]; cv[4] = face[f*3+2];
  cv[1] = VN + (int)selr[feid[f*3]];
  cv[3] = VN + (int)selr[feid[f*3+1]];
  cv[5] = VN + (int)selr[feid[f*3+2]];
  u32 g  = cr[f] - scal[S_GP + c];
  u32 o1 = scal[S_O1];
  for (int j = 0; j < nfc[c]; ++j) {
    u32 row = scal[S_RS + c] + (u32)j*scal[S_GS + c] + g;
    for (int m = 0; m < 3; ++m) {
      int v = cv[tri[c][j][m]];
      nfi[row*3 + m] = v;
      dout[o1 + row*3 + m] = (float)v;
    }
  }
}

__global__ void k_wne(const int* __restrict__ nfi, const u32* __restrict__ scal,
                      float* __restrict__ dout) {
  int i = blockIdx.x*256 + threadIdx.x;
  u32 NEn = scal[S_NEN];
  if (i >= (int)NEn) return;
  u32 NF = scal[S_NF];
  u32 Vp = (u32)VN + scal[S_NUM];
  u32 o2 = scal[S_O2];
  int a, b;
  if ((u32)i < Vp) { a = i; b = i; }
  else {
    u32 j = (u32)i - Vp;
    u32 blk = j / NF, r = j - blk*NF;
    int i0 = (blk == 0) ? 0 : (blk == 1) ? 1 : 2;
    int i1 = (blk == 0) ? 1 : (blk == 1) ? 2 : 0;
    a = nfi[r*3 + i0]; b = nfi[r*3 + i1];
  }
  dout[o2 + i] = (float)a;
  dout[o2 + NEn + i] = (float)b;
}

__global__ void k_wmask(const u32* __restrict__ sel, const float* __restrict__ Y,
                        const u32* __restrict__ scal, float* __restrict__ dout) {
  int e = blockIdx.x*256 + threadIdx.x;
  if (e >= (int)scal[S_E]) return;
  float y = Y[e];
  float yh = sel[e] ? 1.0f : 0.0f;
  dout[scal[S_O3] + e] = (yh - y) + y;
}

// ---------------- host-side drivers ----------------
extern "C" void kernel_launch(void* const* d_in, const int* in_sizes, int n_in,
                              void* d_out, int out_size, void* d_ws, size_t ws_size,
                              hipStream_t stream) {
  const float* x    = (const float*)d_in[0];
  const int*   face = (const int*)d_in[1];
  const int*   divp = (const int*)d_in[4];
  const float* W1s  = (const float*)d_in[5];
  const float* W1n  = (const float*)d_in[6];
  const float* b1   = (const float*)d_in[7];
  const float* W2s  = (const float*)d_in[8];
  const float* W2n  = (const float*)d_in[9];
  const float* b2   = (const float*)d_in[10];
  float* out = (float*)d_out;
  u32* W = (u32*)d_ws;

  u64 *KPA = (u64*)(W+W_KPA), *KPB = (u64*)(W+W_KPB);
  u32 *HIST = W+W_HIST, *HIST2 = W+W_HIST2, *SUMS = W+W_SUMS, *SCAL = W+W_SCAL;
  u32 *TKH = W+W_TKH, *DONE = W+W_DONE;
  u32 *RK = W+W_T64;                  // rank partials (T64 region unused until scan64)
  u64 *T64 = (u64*)(W+W_T64);
  u64 *SUMS64 = (u64*)(W+W_SUMS);

  // 1) keys (+pass0 hist +weight pack +inits); 4-pass u64 radix (no scan_sums dispatches)
  k_keys<<<NB1, 256, 0, stream>>>(face, W1s, W1n, b1, W2s, W2n, (float*)(W+W_PK),
                                  KPA, HIST, TKH, DONE);
  scan_blocks<<<NBS, 256, 0, stream>>>(HIST, HIST, SUMS, NB1*256);
  k_rscat<<<NB1, 256, 0, stream>>>(KPA, KPB, HIST, SUMS,  0, NB1);
  k_rhist<<<NB1, 256, 0, stream>>>(KPB, HIST2,  8, NB1);
  scan_blocks<<<NBS, 256, 0, stream>>>(HIST2, HIST2, SUMS, NB1*256);
  k_rscat<<<NB1, 256, 0, stream>>>(KPB, KPA, HIST2, SUMS,  8, NB1);
  k_rhist<<<NB1, 256, 0, stream>>>(KPA, HIST, 16, NB1);
  scan_blocks<<<NBS, 256, 0, stream>>>(HIST, HIST, SUMS, NB1*256);
  k_rscat<<<NB1, 256, 0, stream>>>(KPA, KPB, HIST, SUMS, 16, NB1);
  k_rhist<<<NB1, 256, 0, stream>>>(KPB, HIST2, 24, NB1);
  scan_blocks<<<NBS, 256, 0, stream>>>(HIST2, HIST2, SUMS, NB1*256);
  k_rscat<<<NB1, 256, 0, stream>>>(KPB, KPA, HIST2, SUMS, 24, NB1);

  // 2) unique + segoff + feid + edge-node outputs + xe
  scan_flagblocks<<<NBS, 256, 0, stream>>>(KPA, RK, SUMS, K3F);
  k_uwrite<<<NB1, 256, 0, stream>>>(KPA, RK, SUMS, x, W+W_SEGOFF, W+W_FEID,
                                    (float*)(W+W_XE), out, SCAL, divp);

  // 3) GSN conv layers (2 edges/thread for ILP)
  k_l12<<<NBL, 256, 0, stream>>>((float*)(W+W_XE), W+W_SEGOFF, KPA, W+W_FEID, SCAL,
                                 (float*)(W+W_PK), (float*)(W+W_P), (float*)(W+W_Q));
  k_scores<<<NBL, 256, 0, stream>>>((float*)(W+W_P), (float*)(W+W_Q), W+W_SEGOFF, KPA,
                                    W+W_FEID, b2, SCAL, (float*)(W+W_Y), W+W_YMAP);

  // 4) exact top-k + selection (no scan64_sums dispatch)
  for (int byte = 3; byte >= 0; --byte)
    k_tkround<<<NBH, 256, 0, stream>>>(W+W_YMAP, SCAL, TKH, DONE, byte);
  scan64_src<<<NBS, 256, 0, stream>>>(W+W_YMAP, SCAL, T64, SUMS64);
  k_sel2<<<NBS, 256, 0, stream>>>(W+W_YMAP, T64, SUMS64, SCAL, W+W_SEL, W+W_SELR);

  // 5) mesh collapse
  k_catfused<<<NBC, 256, 0, stream>>>(W+W_FEID, W+W_SEL, W+W_CAT, W+W_CATH);
  k_catoff<<<1, 256, 0, stream>>>(W+W_CATH, SCAL);
  k_catrank<<<NBC, 256, 0, stream>>>(W+W_CAT, W+W_CATH, W+W_CATR);
  k_wfaces<<<391, 256, 0, stream>>>(face, W+W_CAT, W+W_CATR, W+W_FEID, W+W_SELR, SCAL,
                                    (int*)(W+W_NFI), out);
  k_wne<<<5118, 256, 0, stream>>>((int*)(W+W_NFI), SCAL, out);
  k_wmask<<<NB1, 256, 0, stream>>>(W+W_SEL, (float*)(W+W_Y), SCAL, out);
}